// Round 6
// baseline (248.462 us; speedup 1.0000x reference)
//
#include <hip/hip_runtime.h>
#include <hip/hip_bf16.h>

#define B_   4
#define TQ_  2048
#define TKV_ 2048
#define DM_  1024
#define H_   16
#define DH_  64

// 1/sqrt(DK) * log2(e), folded into Wq/bq so attention exp2 needs no scaling
#define SC_FOLD 0.18033688011112042f

using f32x4  = __attribute__((ext_vector_type(4))) float;
using f32x16 = __attribute__((ext_vector_type(16))) float;
using s16x8  = __attribute__((ext_vector_type(8))) short;

static __device__ __forceinline__ unsigned short f2bf(float f) {
  union { float f; unsigned int u; } v; v.f = f;
  unsigned int r = v.u + 0x7FFFu + ((v.u >> 16) & 1u);
  return (unsigned short)(r >> 16);
}
// packed f32 pair -> 2xbf16 (RNE) in one instruction
static __device__ __forceinline__ unsigned int pk2(float a, float b) {
  unsigned int r;
  asm("v_cvt_pk_bf16_f32 %0, %1, %2" : "=v"(r) : "v"(a), "v"(b));
  return r;
}

// async global->LDS, 16B per lane; LDS dest is wave-uniform base + lane*16
#define GL16(g, l)                                                          \
  __builtin_amdgcn_global_load_lds(                                         \
      (const __attribute__((address_space(1))) unsigned int*)(g),           \
      (__attribute__((address_space(3))) unsigned int*)(l), 16, 0, 0)

// ---------------- transpose + cast + scale: W[K][N] f32 -> WT[N][K] bf16 ----------------
__global__ __launch_bounds__(256) void k_transpose_cast(
    const float* __restrict__ W, unsigned short* __restrict__ WT, int K, int N,
    float scale) {
  __shared__ float t[64][65];
  int n0 = blockIdx.x * 64, k0 = blockIdx.y * 64;
  int tx = threadIdx.x & 63, ty = threadIdx.x >> 6;
#pragma unroll
  for (int i = 0; i < 64; i += 4)
    t[ty + i][tx] = W[(size_t)(k0 + ty + i) * N + n0 + tx];
  __syncthreads();
#pragma unroll
  for (int i = 0; i < 64; i += 4)
    WT[(size_t)(n0 + ty + i) * K + k0 + tx] = f2bf(t[tx][ty + i] * scale);
}

// ---------------- elementwise cast f32 -> bf16 ----------------
__global__ __launch_bounds__(256) void k_cast_bf16(
    const float* __restrict__ in, unsigned short* __restrict__ out, int n4) {
  for (int i = blockIdx.x * 256 + threadIdx.x; i < n4; i += gridDim.x * 256) {
    f32x4 v = *(const f32x4*)(in + (size_t)i * 4);
    unsigned long long u = (unsigned long long)pk2(v[0], v[1]) |
                           ((unsigned long long)pk2(v[2], v[3]) << 32);
    *(unsigned long long*)(out + (size_t)i * 4) = u;
  }
}

// ---------------- GEMM (m97 structure): C = A . BT^T + bias ----------------
template <int MODE>
__global__ __launch_bounds__(256) void k_gemm(
    const unsigned short* __restrict__ A, const unsigned short* __restrict__ BT,
    const float* __restrict__ bias, float bscale, unsigned short* __restrict__ out_a,
    unsigned short* __restrict__ out_b, float* __restrict__ out_f, int Kd) {
  __shared__ __align__(16) unsigned short As[128 * 32];
  __shared__ __align__(16) unsigned short Bs[128 * 32];
  int tid = threadIdx.x, lane = tid & 63, w = tid >> 6;
  int wm = w >> 1, wn = w & 1;

  int nwg = gridDim.x * gridDim.y;
  int bid = blockIdx.y * gridDim.x + blockIdx.x;
  int cpx = nwg >> 3;
  int sw = (bid & 7) * cpx + (bid >> 3);
  int bx = sw % gridDim.x, by = sw / gridDim.x;
  int m0 = by * 128, n0 = bx * 128;

  int srow = w * 32 + (lane >> 2);
  int scol = (lane & 3) * 8;
  const unsigned short* gA0 = A + (size_t)(m0 + srow) * Kd + scol;
  const unsigned short* gA1 = gA0 + (size_t)16 * Kd;
  const unsigned short* gB0 = BT + (size_t)(n0 + srow) * Kd + scol;
  const unsigned short* gB1 = gB0 + (size_t)16 * Kd;
  unsigned short* lA0 = As + w * 1024;
  unsigned short* lA1 = As + w * 1024 + 512;
  unsigned short* lB0 = Bs + w * 1024;
  unsigned short* lB1 = Bs + w * 1024 + 512;

  f32x4 acc[4][4];
#pragma unroll
  for (int i = 0; i < 4; ++i)
#pragma unroll
    for (int j = 0; j < 4; ++j) acc[i][j] = (f32x4){0.f, 0.f, 0.f, 0.f};

  for (int k0 = 0; k0 < Kd; k0 += 32) {
    __syncthreads();
    GL16(gA0 + k0, lA0);
    GL16(gA1 + k0, lA1);
    GL16(gB0 + k0, lB0);
    GL16(gB1 + k0, lB1);
    __syncthreads();

    s16x8 af[4], bf[4];
#pragma unroll
    for (int i = 0; i < 4; ++i) {
      af[i] = *(const s16x8*)(As + (wm * 64 + i * 16 + (lane & 15)) * 32 + (lane >> 4) * 8);
      bf[i] = *(const s16x8*)(Bs + (wn * 64 + i * 16 + (lane & 15)) * 32 + (lane >> 4) * 8);
    }
#pragma unroll
    for (int mi = 0; mi < 4; ++mi)
#pragma unroll
      for (int ni = 0; ni < 4; ++ni)
        acc[mi][ni] = __builtin_amdgcn_mfma_f32_16x16x32_bf16(af[mi], bf[ni], acc[mi][ni], 0, 0, 0);
  }

#pragma unroll
  for (int mi = 0; mi < 4; ++mi) {
#pragma unroll
    for (int ni = 0; ni < 4; ++ni) {
      int col = n0 + wn * 64 + ni * 16 + (lane & 15);
      int rbase = m0 + wm * 64 + mi * 16 + (lane >> 4) * 4;
      float bv = bias[col] * bscale;
      if (MODE == 1 && col >= H_ * DH_) {
        int c2 = col - H_ * DH_;
        int h = c2 >> 6, d = c2 & 63;
        int b = rbase >> 11, t = rbase & 2047;
        union { unsigned short h4[4]; unsigned long long u; } p;
#pragma unroll
        for (int r = 0; r < 4; ++r) p.h4[r] = f2bf(acc[mi][ni][r] + bv);
        *(unsigned long long*)(out_b + ((((size_t)b * H_ + h) * DH_ + d) * TKV_ + t)) = p.u;
      } else {
#pragma unroll
        for (int r = 0; r < 4; ++r) {
          float v = acc[mi][ni][r] + bv;
          int m = rbase + r;
          if (MODE == 0) {
            int b = m >> 11, t = m & 2047;
            int h = col >> 6, d = col & 63;
            out_a[(((size_t)b * H_ + h) * TQ_ + t) * DH_ + d] = f2bf(v);
          } else if (MODE == 1) {
            int b = m >> 11, t = m & 2047;
            int h = col >> 6, d = col & 63;
            out_a[(((size_t)b * H_ + h) * TKV_ + t) * DH_ + d] = f2bf(v);
          } else {
            out_f[(size_t)m * DM_ + col] = v;
          }
        }
      }
    }
  }
}

// ---------------- flash attention: 64 q-rows/wave, kv-split, paired q-tiles ----------------
// grid (4, 64) x 512 threads = 8 waves. Group g = w>>2 takes one contiguous KV
// half; wave wq = w&3 owns 64 q-rows (two 32-col B-frag sets). Each K/V
// ds_read_b128 feeds 2 MFMAs (halved LDS traffic vs 32q/wave). Merge via LDS.
__global__ __launch_bounds__(512, 2) void k_attn(
    const unsigned short* __restrict__ Qb, const unsigned short* __restrict__ Kb,
    const unsigned short* __restrict__ Vtb, const unsigned char* __restrict__ mask,
    const int* __restrict__ cflag, unsigned short* __restrict__ Ob) {
  __shared__ __align__(16) unsigned short KVbuf[4][4096];  // 2 groups x (K,V); merge alias 32KB
  __shared__ float bias_lds[2][64];
  __shared__ float red[8][64];
  __shared__ float red2[8][64];
  __shared__ int s_any;

  // XCD head-locality swizzle: 4 q-blocks per head, 8 heads per XCD
  int bid = blockIdx.y * gridDim.x + blockIdx.x;
  int r8 = bid & 7, q8 = bid >> 3;
  int bh = r8 * 8 + (q8 >> 2);
  int bx = q8 & 3;

  int b = bh >> 4, h = bh & 15;
  int tid = threadIdx.x, lane = tid & 63, w = tid >> 6;
  int g = w >> 2, wq = w & 3, tg = tid & 255;
  int hi = lane >> 5, l31 = lane & 31, l7 = lane & 7;
  const unsigned short* Qp = Qb + (size_t)bh * TQ_ * DH_;
  const char* Kp = (const char*)(Kb + (size_t)bh * TKV_ * DH_);
  const char* Vp = (const char*)(Vtb + (size_t)bh * DH_ * TKV_);
  const unsigned char* mp = mask + (size_t)b * TKV_;
  int causal = cflag[0];
  char* kbase = (char*)&KVbuf[g * 2][0];
  char* vbase = (char*)&KVbuf[g * 2 + 1][0];
  float* mrg = (float*)KVbuf;

  if (tid == 0) s_any = 0;
  __syncthreads();
  {
    int any = 0;
    for (int i = tid; i < TKV_; i += 512) any |= mp[i];
    if (any) s_any = 1;
  }
  __syncthreads();
  const int has_mask = s_any;

#pragma unroll 1
  for (int pass = 0; pass < 2; ++pass) {
    int qb = (pass ? (7 - bx) : bx) * 256;
    int qw = qb + wq * 64;
    int qrow = qw + l31;          // set0 q; set1 q = qrow+32

    s16x8 bQ0[4], bQ1[4];
#pragma unroll
    for (int kk = 0; kk < 4; ++kk) {
      bQ0[kk] = *(const s16x8*)(Qp + (size_t)qrow * DH_ + kk * 16 + hi * 8);
      bQ1[kk] = *(const s16x8*)(Qp + (size_t)(qrow + 32) * DH_ + kk * 16 + hi * 8);
    }

    f32x16 aO00, aO01, aO10, aO11;  // [set][dt]
#pragma unroll
    for (int i = 0; i < 16; ++i) { aO00[i] = 0.f; aO01[i] = 0.f; aO10[i] = 0.f; aO11[i] = 0.f; }
    float m0 = -INFINITY, l0 = 0.f, m1 = -INFINITY, l1 = 0.f;

    int kv_end = causal ? (qb + 256) : TKV_;
    int half = kv_end >> 1;               // multiple of 64
    int g_start = g ? half : 0;
    int nIter = half >> 6;

    for (int it = 0; it < nIter; ++it) {
      int kv0 = g_start + it * 64;
      __syncthreads();
      {  // per-group staging of K tile and V^T tile (XOR-swizzled)
        int row = tg >> 2;
        int cb0 = (tg & 3) * 16;
#pragma unroll
        for (int p = 0; p < 2; ++p) {
          int cb = cb0 + p * 64;
          int sw = cb ^ ((row & 7) << 4);
          s16x8 kvv = *(const s16x8*)(Kp + ((size_t)(kv0 + row) * 128 + cb));
          *(s16x8*)(kbase + row * 128 + sw) = kvv;
          s16x8 vvv = *(const s16x8*)(Vp + (((size_t)row * TKV_ + kv0) * 2 + cb));
          *(s16x8*)(vbase + row * 128 + sw) = vvv;
        }
        if (has_mask && tg < 64) bias_lds[g][tg] = mp[kv0 + tg] ? -1e30f : 0.0f;
      }
      __syncthreads();
      if (causal && kv0 >= qw + 64) continue;  // wave fully above diagonal

      // S^T = K . Q^T for both q-sets; each aK read feeds 2 MFMAs
      f32x16 sT0[2], sT1[2];
#pragma unroll
      for (int i = 0; i < 16; ++i) { sT0[0][i] = 0.f; sT0[1][i] = 0.f; sT1[0][i] = 0.f; sT1[1][i] = 0.f; }
      __builtin_amdgcn_s_setprio(1);
#pragma unroll
      for (int s = 0; s < 2; ++s) {
#pragma unroll
        for (int kk = 0; kk < 4; ++kk) {
          s16x8 aK = *(const s16x8*)(kbase + (s * 32 + l31) * 128 +
                                     ((kk * 32 + hi * 16) ^ (l7 << 4)));
          sT0[s] = __builtin_amdgcn_mfma_f32_32x32x16_bf16(aK, bQ0[kk], sT0[s], 0, 0, 0);
          sT1[s] = __builtin_amdgcn_mfma_f32_32x32x16_bf16(aK, bQ1[kk], sT1[s], 0, 0, 0);
        }
      }
      __builtin_amdgcn_s_setprio(0);

      int diag = causal && (kv0 + 64 > qw);  // wave-uniform
      float mx0 = -INFINITY, mx1 = -INFINITY;
      if (diag || has_mask) {
#pragma unroll
        for (int s = 0; s < 2; ++s)
#pragma unroll
          for (int r = 0; r < 16; ++r) {
            int kvloc = s * 32 + (r & 3) + 8 * (r >> 2) + 4 * hi;
            float sv0 = sT0[s][r], sv1 = sT1[s][r];
            if (has_mask) { sv0 += bias_lds[g][kvloc]; sv1 += bias_lds[g][kvloc]; }
            if (causal && (kv0 + kvloc) > qrow) sv0 = -1e30f;
            if (causal && (kv0 + kvloc) > qrow + 32) sv1 = -1e30f;
            sT0[s][r] = sv0; sT1[s][r] = sv1;
            mx0 = fmaxf(mx0, sv0); mx1 = fmaxf(mx1, sv1);
          }
      } else {
#pragma unroll
        for (int s = 0; s < 2; ++s)
#pragma unroll
          for (int r = 0; r < 16; ++r) {
            mx0 = fmaxf(mx0, sT0[s][r]);
            mx1 = fmaxf(mx1, sT1[s][r]);
          }
      }
      mx0 = fmaxf(mx0, __shfl_xor(mx0, 32));
      mx1 = fmaxf(mx1, __shfl_xor(mx1, 32));

      // T13 defer-rescale (joint over both sets)
      if (!__all(fmaxf(mx0 - m0, mx1 - m1) <= 8.0f)) {
        float mn0 = fmaxf(m0, mx0), mn1 = fmaxf(m1, mx1);
        float s0 = exp2f(m0 - mn0), s1 = exp2f(m1 - mn1);
        m0 = mn0; m1 = mn1; l0 *= s0; l1 *= s1;
        red[w][l31] = s0; red[w][32 + l31] = s1;
#pragma unroll
        for (int r = 0; r < 16; ++r) {
          int R = (r & 3) + 8 * (r >> 2) + 4 * hi;
          float f0 = red[w][R], f1 = red[w][32 + R];
          aO00[r] *= f0; aO01[r] *= f0;
          aO10[r] *= f1; aO11[r] *= f1;
        }
      }

      float ls0 = 0.f, ls1 = 0.f;
#pragma unroll
      for (int s = 0; s < 2; ++s)
#pragma unroll
        for (int r = 0; r < 16; ++r) {
          float p0 = exp2f(sT0[s][r] - m0);
          float p1 = exp2f(sT1[s][r] - m1);
          sT0[s][r] = p0; sT1[s][r] = p1;
          ls0 += p0; ls1 += p1;
        }
      ls0 += __shfl_xor(ls0, 32);
      ls1 += __shfl_xor(ls1, 32);
      l0 += ls0; l1 += ls1;

      // P -> A-frag (cvt_pk + shfl) for both sets; each vf read feeds 2 MFMAs
#pragma unroll
      for (int c = 0; c < 4; ++c) {
        int s = c >> 1, kk = c & 1;
        union { unsigned int u[4]; s16x8 v; } pf0, pf1;
        {
          unsigned int x0 = pk2(sT0[s][8 * kk + 0], sT0[s][8 * kk + 1]);
          unsigned int y0 = pk2(sT0[s][8 * kk + 2], sT0[s][8 * kk + 3]);
          unsigned int x1 = pk2(sT0[s][8 * kk + 4], sT0[s][8 * kk + 5]);
          unsigned int y1 = pk2(sT0[s][8 * kk + 6], sT0[s][8 * kk + 7]);
          unsigned int sx0 = __shfl_xor(x0, 32), sy0 = __shfl_xor(y0, 32);
          unsigned int sx1 = __shfl_xor(x1, 32), sy1 = __shfl_xor(y1, 32);
          pf0.u[0] = hi ? sx1 : x0;
          pf0.u[1] = hi ? sy1 : y0;
          pf0.u[2] = hi ? x1 : sx0;
          pf0.u[3] = hi ? y1 : sy0;
        }
        {
          unsigned int x0 = pk2(sT1[s][8 * kk + 0], sT1[s][8 * kk + 1]);
          unsigned int y0 = pk2(sT1[s][8 * kk + 2], sT1[s][8 * kk + 3]);
          unsigned int x1 = pk2(sT1[s][8 * kk + 4], sT1[s][8 * kk + 5]);
          unsigned int y1 = pk2(sT1[s][8 * kk + 6], sT1[s][8 * kk + 7]);
          unsigned int sx0 = __shfl_xor(x0, 32), sy0 = __shfl_xor(y0, 32);
          unsigned int sx1 = __shfl_xor(x1, 32), sy1 = __shfl_xor(y1, 32);
          pf1.u[0] = hi ? sx1 : x0;
          pf1.u[1] = hi ? sy1 : y0;
          pf1.u[2] = hi ? x1 : sx0;
          pf1.u[3] = hi ? y1 : sy0;
        }
        __builtin_amdgcn_s_setprio(1);
#pragma unroll
        for (int dt = 0; dt < 2; ++dt) {
          s16x8 vf = *(const s16x8*)(vbase + (dt * 32 + l31) * 128 +
                                     ((c * 32 + hi * 16) ^ (l7 << 4)));
          if (dt == 0) {
            aO00 = __builtin_amdgcn_mfma_f32_32x32x16_bf16(pf0.v, vf, aO00, 0, 0, 0);
            aO10 = __builtin_amdgcn_mfma_f32_32x32x16_bf16(pf1.v, vf, aO10, 0, 0, 0);
          } else {
            aO01 = __builtin_amdgcn_mfma_f32_32x32x16_bf16(pf0.v, vf, aO01, 0, 0, 0);
            aO11 = __builtin_amdgcn_mfma_f32_32x32x16_bf16(pf1.v, vf, aO11, 0, 0, 0);
          }
        }
        __builtin_amdgcn_s_setprio(0);
      }
    }

    // ---- merge group-1 partials into group-0 (set-by-set), then epilogue ----
    __syncthreads();
    float* mb = mrg + (size_t)wq * 2048 + lane * 32;
    if (g == 1) {
      red[w][l31] = m0; red[w][32 + l31] = m1;
      red2[w][l31] = l0; red2[w][32 + l31] = l1;
#pragma unroll
      for (int cc = 0; cc < 4; ++cc) {
        f32x4 v0 = {aO00[cc * 4 + 0], aO00[cc * 4 + 1], aO00[cc * 4 + 2], aO00[cc * 4 + 3]};
        *(f32x4*)(mb + (((0 * 4 + cc) ^ l7) << 2)) = v0;
        f32x4 v1 = {aO01[cc * 4 + 0], aO01[cc * 4 + 1], aO01[cc * 4 + 2], aO01[cc * 4 + 3]};
        *(f32x4*)(mb + (((1 * 4 + cc) ^ l7) << 2)) = v1;
      }
    }
    __syncthreads();
    float sA0, sB0, sA1, sB1;
    if (g == 0) {
      float mB0 = red[w + 4][l31], mB1 = red[w + 4][32 + l31];
      float lB0 = red2[w + 4][l31], lB1 = red2[w + 4][32 + l31];
      float mn0 = fmaxf(m0, mB0), mn1 = fmaxf(m1, mB1);
      sA0 = exp2f(m0 - mn0); sB0 = exp2f(mB0 - mn0);
      sA1 = exp2f(m1 - mn1); sB1 = exp2f(mB1 - mn1);
      l0 = l0 * sA0 + lB0 * sB0;
      l1 = l1 * sA1 + lB1 * sB1;
      red[w][l31] = sA0; red[w][32 + l31] = sA1;
      red2[w][l31] = sB0; red2[w][32 + l31] = sB1;
#pragma unroll
      for (int dt = 0; dt < 2; ++dt)
#pragma unroll
        for (int cc = 0; cc < 4; ++cc) {
          f32x4 t = *(const f32x4*)(mb + (((dt * 4 + cc) ^ l7) << 2));
#pragma unroll
          for (int j = 0; j < 4; ++j) {
            int r = cc * 4 + j;
            int R = (r & 3) + 8 * (r >> 2) + 4 * hi;
            float fa = red[w][R], fb = red2[w][R];
            if (dt == 0) aO00[r] = aO00[r] * fa + t[j] * fb;
            else         aO01[r] = aO01[r] * fa + t[j] * fb;
          }
        }
    }
    __syncthreads();
    if (g == 1) {
#pragma unroll
      for (int cc = 0; cc < 4; ++cc) {
        f32x4 v0 = {aO10[cc * 4 + 0], aO10[cc * 4 + 1], aO10[cc * 4 + 2], aO10[cc * 4 + 3]};
        *(f32x4*)(mb + (((0 * 4 + cc) ^ l7) << 2)) = v0;
        f32x4 v1 = {aO11[cc * 4 + 0], aO11[cc * 4 + 1], aO11[cc * 4 + 2], aO11[cc * 4 + 3]};
        *(f32x4*)(mb + (((1 * 4 + cc) ^ l7) << 2)) = v1;
      }
    }
    __syncthreads();
    if (g == 0) {
#pragma unroll
      for (int dt = 0; dt < 2; ++dt)
#pragma unroll
        for (int cc = 0; cc < 4; ++cc) {
          f32x4 t = *(const f32x4*)(mb + (((dt * 4 + cc) ^ l7) << 2));
#pragma unroll
          for (int j = 0; j < 4; ++j) {
            int r = cc * 4 + j;
            int R = (r & 3) + 8 * (r >> 2) + 4 * hi;
            float fa = red[w][32 + R], fb = red2[w][32 + R];
            if (dt == 0) aO10[r] = aO10[r] * fa + t[j] * fb;
            else         aO11[r] = aO11[r] * fa + t[j] * fb;
          }
        }

      red[w][l31] = 1.0f / l0;
      red[w][32 + l31] = 1.0f / l1;
#pragma unroll
      for (int r = 0; r < 16; ++r) {
        int R = (r & 3) + 8 * (r >> 2) + 4 * hi;
        float f0 = red[w][R], f1 = red[w][32 + R];
        int qg0 = qw + R, qg1 = qw + 32 + R;
        size_t base0 = ((size_t)b * TQ_ + qg0) * DM_ + h * DH_ + l31;
        size_t base1 = ((size_t)b * TQ_ + qg1) * DM_ + h * DH_ + l31;
        Ob[base0] = f2bf(aO00[r] * f0);
        Ob[base0 + 32] = f2bf(aO01[r] * f0);
        Ob[base1] = f2bf(aO10[r] * f1);
        Ob[base1 + 32] = f2bf(aO11[r] * f1);
      }
    }
  }
}

extern "C" void kernel_launch(void* const* d_in, const int* in_sizes, int n_in,
                              void* d_out, int out_size, void* d_ws, size_t ws_size,
                              hipStream_t stream) {
  const float* xq  = (const float*)d_in[0];
  const float* xkv = (const float*)d_in[1];
  const unsigned char* mask = (const unsigned char*)d_in[2];
  const float* Wq  = (const float*)d_in[3];
  const float* bq  = (const float*)d_in[4];
  const float* Wkv = (const float*)d_in[5];
  const float* bkv = (const float*)d_in[6];
  const float* Wo  = (const float*)d_in[7];
  const float* bo  = (const float*)d_in[8];
  const int* cflag = (const int*)d_in[9];
  float* out = (float*)d_out;

  char* ws = (char*)d_ws;
  unsigned short* WqT  = (unsigned short*)(ws);                       // 2 MiB
  unsigned short* WkvT = (unsigned short*)(ws + ((size_t)2 << 20));   // 4 MiB
  unsigned short* WoT  = (unsigned short*)(ws + ((size_t)6 << 20));   // 2 MiB
  unsigned short* Qb   = (unsigned short*)(ws + ((size_t)8 << 20));   // [B,H,TQ,64]
  unsigned short* Kb   = (unsigned short*)(ws + ((size_t)24 << 20));  // [B,H,TKV,64]
  unsigned short* Vb   = (unsigned short*)(ws + ((size_t)40 << 20));  // [B,H,64,TKV]
  unsigned short* Xr   = (unsigned short*)(ws + ((size_t)56 << 20));  // Aq -> Akv -> Ob
  unsigned short* Ob   = Xr;

  k_transpose_cast<<<dim3(16, 16), 256, 0, stream>>>(Wq, WqT, 1024, 1024, SC_FOLD);
  k_transpose_cast<<<dim3(32, 16), 256, 0, stream>>>(Wkv, WkvT, 1024, 2048, 1.0f);
  k_transpose_cast<<<dim3(16, 16), 256, 0, stream>>>(Wo, WoT, 1024, 1024, 1.0f);

  k_cast_bf16<<<2048, 256, 0, stream>>>(xq, Xr, B_ * TQ_ * DM_ / 4);
  k_gemm<0><<<dim3(8, 64), 256, 0, stream>>>(Xr, WqT, bq, SC_FOLD, Qb, nullptr, nullptr, 1024);

  k_cast_bf16<<<2048, 256, 0, stream>>>(xkv, Xr, B_ * TKV_ * DM_ / 4);
  k_gemm<1><<<dim3(16, 64), 256, 0, stream>>>(Xr, WkvT, bkv, 1.0f, Kb, Vb, nullptr, 1024);

  k_attn<<<dim3(4, B_ * H_), 512, 0, stream>>>(Qb, Kb, Vb, mask, cflag, Ob);

  k_gemm<2><<<dim3(8, 64), 256, 0, stream>>>(Ob, WoT, bo, 1.0f, nullptr, nullptr, out, 1024);
}

// Round 7
// 246.674 us; speedup vs baseline: 1.0072x; 1.0072x over previous
//
#include <hip/hip_runtime.h>
#include <hip/hip_bf16.h>

#define B_   4
#define TQ_  2048
#define TKV_ 2048
#define DM_  1024
#define H_   16
#define DH_  64

// 1/sqrt(DK) * log2(e), folded into Wq/bq so attention exp2 needs no scaling
#define SC_FOLD 0.18033688011112042f

using f32x4  = __attribute__((ext_vector_type(4))) float;
using f32x16 = __attribute__((ext_vector_type(16))) float;
using s16x8  = __attribute__((ext_vector_type(8))) short;

static __device__ __forceinline__ unsigned short f2bf(float f) {
  union { float f; unsigned int u; } v; v.f = f;
  unsigned int r = v.u + 0x7FFFu + ((v.u >> 16) & 1u);
  return (unsigned short)(r >> 16);
}
// packed f32 pair -> 2xbf16 (RNE) in one instruction
static __device__ __forceinline__ unsigned int pk2(float a, float b) {
  unsigned int r;
  asm("v_cvt_pk_bf16_f32 %0, %1, %2" : "=v"(r) : "v"(a), "v"(b));
  return r;
}

// async global->LDS, 16B per lane; LDS dest is wave-uniform base + lane*16
#define GL16(g, l)                                                          \
  __builtin_amdgcn_global_load_lds(                                         \
      (const __attribute__((address_space(1))) unsigned int*)(g),           \
      (__attribute__((address_space(3))) unsigned int*)(l), 16, 0, 0)

// ---------------- transpose + cast + scale: W[K][N] f32 -> WT[N][K] bf16 ----------------
__global__ __launch_bounds__(256) void k_transpose_cast(
    const float* __restrict__ W, unsigned short* __restrict__ WT, int K, int N,
    float scale) {
  __shared__ float t[64][65];
  int n0 = blockIdx.x * 64, k0 = blockIdx.y * 64;
  int tx = threadIdx.x & 63, ty = threadIdx.x >> 6;
#pragma unroll
  for (int i = 0; i < 64; i += 4)
    t[ty + i][tx] = W[(size_t)(k0 + ty + i) * N + n0 + tx];
  __syncthreads();
#pragma unroll
  for (int i = 0; i < 64; i += 4)
    WT[(size_t)(n0 + ty + i) * K + k0 + tx] = f2bf(t[tx][ty + i] * scale);
}

// ---------------- elementwise cast f32 -> bf16 ----------------
__global__ __launch_bounds__(256) void k_cast_bf16(
    const float* __restrict__ in, unsigned short* __restrict__ out, int n4) {
  for (int i = blockIdx.x * 256 + threadIdx.x; i < n4; i += gridDim.x * 256) {
    f32x4 v = *(const f32x4*)(in + (size_t)i * 4);
    unsigned long long u = (unsigned long long)pk2(v[0], v[1]) |
                           ((unsigned long long)pk2(v[2], v[3]) << 32);
    *(unsigned long long*)(out + (size_t)i * 4) = u;
  }
}

// ---------------- GEMM (m97 structure): C = A . BT^T + bias ----------------
template <int MODE>
__global__ __launch_bounds__(256) void k_gemm(
    const unsigned short* __restrict__ A, const unsigned short* __restrict__ BT,
    const float* __restrict__ bias, float bscale, unsigned short* __restrict__ out_a,
    unsigned short* __restrict__ out_b, float* __restrict__ out_f, int Kd) {
  __shared__ __align__(16) unsigned short As[128 * 32];
  __shared__ __align__(16) unsigned short Bs[128 * 32];
  int tid = threadIdx.x, lane = tid & 63, w = tid >> 6;
  int wm = w >> 1, wn = w & 1;

  int nwg = gridDim.x * gridDim.y;
  int bid = blockIdx.y * gridDim.x + blockIdx.x;
  int cpx = nwg >> 3;
  int sw = (bid & 7) * cpx + (bid >> 3);
  int bx = sw % gridDim.x, by = sw / gridDim.x;
  int m0 = by * 128, n0 = bx * 128;

  int srow = w * 32 + (lane >> 2);
  int scol = (lane & 3) * 8;
  const unsigned short* gA0 = A + (size_t)(m0 + srow) * Kd + scol;
  const unsigned short* gA1 = gA0 + (size_t)16 * Kd;
  const unsigned short* gB0 = BT + (size_t)(n0 + srow) * Kd + scol;
  const unsigned short* gB1 = gB0 + (size_t)16 * Kd;
  unsigned short* lA0 = As + w * 1024;
  unsigned short* lA1 = As + w * 1024 + 512;
  unsigned short* lB0 = Bs + w * 1024;
  unsigned short* lB1 = Bs + w * 1024 + 512;

  f32x4 acc[4][4];
#pragma unroll
  for (int i = 0; i < 4; ++i)
#pragma unroll
    for (int j = 0; j < 4; ++j) acc[i][j] = (f32x4){0.f, 0.f, 0.f, 0.f};

  for (int k0 = 0; k0 < Kd; k0 += 32) {
    __syncthreads();
    GL16(gA0 + k0, lA0);
    GL16(gA1 + k0, lA1);
    GL16(gB0 + k0, lB0);
    GL16(gB1 + k0, lB1);
    __syncthreads();

    s16x8 af[4], bf[4];
#pragma unroll
    for (int i = 0; i < 4; ++i) {
      af[i] = *(const s16x8*)(As + (wm * 64 + i * 16 + (lane & 15)) * 32 + (lane >> 4) * 8);
      bf[i] = *(const s16x8*)(Bs + (wn * 64 + i * 16 + (lane & 15)) * 32 + (lane >> 4) * 8);
    }
#pragma unroll
    for (int mi = 0; mi < 4; ++mi)
#pragma unroll
      for (int ni = 0; ni < 4; ++ni)
        acc[mi][ni] = __builtin_amdgcn_mfma_f32_16x16x32_bf16(af[mi], bf[ni], acc[mi][ni], 0, 0, 0);
  }

#pragma unroll
  for (int mi = 0; mi < 4; ++mi) {
#pragma unroll
    for (int ni = 0; ni < 4; ++ni) {
      int col = n0 + wn * 64 + ni * 16 + (lane & 15);
      int rbase = m0 + wm * 64 + mi * 16 + (lane >> 4) * 4;
      float bv = bias[col] * bscale;
      if (MODE == 1 && col >= H_ * DH_) {
        int c2 = col - H_ * DH_;
        int h = c2 >> 6, d = c2 & 63;
        int b = rbase >> 11, t = rbase & 2047;
        union { unsigned short h4[4]; unsigned long long u; } p;
#pragma unroll
        for (int r = 0; r < 4; ++r) p.h4[r] = f2bf(acc[mi][ni][r] + bv);
        *(unsigned long long*)(out_b + ((((size_t)b * H_ + h) * DH_ + d) * TKV_ + t)) = p.u;
      } else {
#pragma unroll
        for (int r = 0; r < 4; ++r) {
          float v = acc[mi][ni][r] + bv;
          int m = rbase + r;
          if (MODE == 0) {
            int b = m >> 11, t = m & 2047;
            int h = col >> 6, d = col & 63;
            out_a[(((size_t)b * H_ + h) * TQ_ + t) * DH_ + d] = f2bf(v);
          } else if (MODE == 1) {
            int b = m >> 11, t = m & 2047;
            int h = col >> 6, d = col & 63;
            out_a[(((size_t)b * H_ + h) * TKV_ + t) * DH_ + d] = f2bf(v);
          } else {
            out_f[(size_t)m * DM_ + col] = v;
          }
        }
      }
    }
  }
}

// ---------------- flash attention: swapped-QK^T, dbuf async K/V staging ----------------
// grid (8, 64) x 256 threads = 4 waves x 32 q-rows; paired q-tiles (bx, 15-bx).
// K/V double-buffered in LDS via global_load_lds with pre-swizzled global source
// (rule #21): stage tile i+1 during compute of tile i; ONE barrier per tile.
__global__ __launch_bounds__(256, 4) void k_attn(
    const unsigned short* __restrict__ Qb, const unsigned short* __restrict__ Kb,
    const unsigned short* __restrict__ Vtb, const unsigned char* __restrict__ mask,
    const int* __restrict__ cflag, unsigned short* __restrict__ Ob) {
  __shared__ __align__(16) unsigned short Kt[2][4096];  // [buf][kv][d] XOR-swizzled
  __shared__ __align__(16) unsigned short Vt[2][4096];  // [buf][d][kv] XOR-swizzled
  __shared__ float red[4][32];
  __shared__ int s_any;

  // XCD head-locality swizzle: 8 q-blocks of a head on one XCD
  int bid = blockIdx.y * gridDim.x + blockIdx.x;
  int r8 = bid & 7, q8 = bid >> 3;
  int bh = r8 * 8 + (q8 >> 3);
  int bx = q8 & 7;

  int b = bh >> 4, h = bh & 15;
  int tid = threadIdx.x, lane = tid & 63, w = tid >> 6;
  int hi = lane >> 5, l31 = lane & 31, l7 = lane & 7;
  const unsigned short* Qp = Qb + (size_t)bh * TQ_ * DH_;
  const char* Kp = (const char*)(Kb + (size_t)bh * TKV_ * DH_);
  const char* Vp = (const char*)(Vtb + (size_t)bh * DH_ * TKV_);
  const unsigned char* mp = mask + (size_t)b * TKV_;
  int causal = cflag[0];

  // staging geometry (per wave, per issue p): 64 lanes x 16B = 1024B
  // linear LDS offset o = w*1024 + p*4096 + lane*16 -> row = p*32+w*8+(lane>>3),
  // x = (lane&7)*16; pre-swizzled global byte = x ^ ((row&7)<<4)
  int st_row = w * 8 + (lane >> 3);
  int st_gx = ((lane & 7) << 4) ^ ((lane >> 3) << 4);

#define STAGE_KV(bufi, kv0)                                                   \
  {                                                                           \
    _Pragma("unroll")                                                         \
    for (int p = 0; p < 2; ++p) {                                             \
      int row = p * 32 + st_row;                                              \
      GL16(Kp + (size_t)((kv0) + row) * 128 + st_gx,                          \
           (char*)(&Kt[bufi][0]) + w * 1024 + p * 4096);                      \
      GL16(Vp + ((size_t)row * TKV_ + (kv0)) * 2 + st_gx,                     \
           (char*)(&Vt[bufi][0]) + w * 1024 + p * 4096);                      \
    }                                                                         \
  }

  if (tid == 0) s_any = 0;
  __syncthreads();
  {
    int any = 0;
    for (int i = tid; i < TKV_; i += 256) any |= mp[i];
    if (any) s_any = 1;
  }
  __syncthreads();
  const int has_mask = s_any;

#pragma unroll 1
  for (int pass = 0; pass < 2; ++pass) {
    int qb = (pass ? (15 - bx) : bx) * 128;
    int qw = qb + w * 32;
    int qrow = qw + l31;

    s16x8 bQ[4];
#pragma unroll
    for (int kk = 0; kk < 4; ++kk)
      bQ[kk] = *(const s16x8*)(Qp + (size_t)qrow * DH_ + kk * 16 + hi * 8);

    f32x16 accO[2];
#pragma unroll
    for (int i = 0; i < 16; ++i) { accO[0][i] = 0.f; accO[1][i] = 0.f; }
    float m_run = -INFINITY, l_run = 0.f;

    int nT = (causal ? (qb + 128) : TKV_) >> 6;

    // prologue: stage tile 0 into buf 0
    STAGE_KV(0, 0);
    asm volatile("s_waitcnt vmcnt(0)" ::: "memory");
    __syncthreads();

    int cur = 0;
#pragma unroll 1
    for (int it = 0; it < nT; ++it) {
      int kv0 = it << 6;
      if (it + 1 < nT) STAGE_KV(cur ^ 1, kv0 + 64);  // async prefetch

      if (!(causal && kv0 >= qw + 32)) {
        char* kbase = (char*)&Kt[cur][0];
        char* vbase = (char*)&Vt[cur][0];

        // S^T = K . Q^T  (64 kv x 32 q per wave, two 32x32 sub-tiles)
        f32x16 sT[2];
#pragma unroll
        for (int i = 0; i < 16; ++i) { sT[0][i] = 0.f; sT[1][i] = 0.f; }
        __builtin_amdgcn_s_setprio(1);
#pragma unroll
        for (int s = 0; s < 2; ++s) {
#pragma unroll
          for (int kk = 0; kk < 4; ++kk) {
            s16x8 aK = *(const s16x8*)(kbase + (s * 32 + l31) * 128 +
                                       ((kk * 32 + hi * 16) ^ (l7 << 4)));
            sT[s] = __builtin_amdgcn_mfma_f32_32x32x16_bf16(aK, bQ[kk], sT[s], 0, 0, 0);
          }
        }
        __builtin_amdgcn_s_setprio(0);

        int diag = causal && (kv0 + 64 > qw);  // wave-uniform
        float mx = -INFINITY;
        if (diag || has_mask) {
#pragma unroll
          for (int s = 0; s < 2; ++s)
#pragma unroll
            for (int r = 0; r < 16; ++r) {
              int kvloc = s * 32 + (r & 3) + 8 * (r >> 2) + 4 * hi;
              float sv = sT[s][r];
              if (has_mask) sv += (mp[kv0 + kvloc] ? -1e30f : 0.0f);
              if (diag && (kv0 + kvloc) > qrow) sv = -1e30f;
              sT[s][r] = sv;
              mx = fmaxf(mx, sv);
            }
        } else {
#pragma unroll
          for (int s = 0; s < 2; ++s)
#pragma unroll
            for (int r = 0; r < 16; ++r) mx = fmaxf(mx, sT[s][r]);
        }
        mx = fmaxf(mx, __shfl_xor(mx, 32));

        // T13 defer-rescale
        if (!__all(mx - m_run <= 8.0f)) {
          float mnew = fmaxf(m_run, mx);
          float sc_o = exp2f(m_run - mnew);
          m_run = mnew;
          l_run *= sc_o;
          red[w][l31] = sc_o;
#pragma unroll
          for (int r = 0; r < 16; ++r) {
            float f = red[w][(r & 3) + 8 * (r >> 2) + 4 * hi];
            accO[0][r] *= f;
            accO[1][r] *= f;
          }
        }

        float ls = 0.f;
#pragma unroll
        for (int s = 0; s < 2; ++s)
#pragma unroll
          for (int r = 0; r < 16; ++r) {
            float p = exp2f(sT[s][r] - m_run);
            sT[s][r] = p;
            ls += p;
          }
        ls += __shfl_xor(ls, 32);
        l_run += ls;

        // P -> A-frag (cvt_pk + 4 shfl per k-chunk) + PV
#pragma unroll
        for (int c = 0; c < 4; ++c) {
          int s = c >> 1, kk = c & 1;
          unsigned int x0 = pk2(sT[s][8 * kk + 0], sT[s][8 * kk + 1]);
          unsigned int y0 = pk2(sT[s][8 * kk + 2], sT[s][8 * kk + 3]);
          unsigned int x1 = pk2(sT[s][8 * kk + 4], sT[s][8 * kk + 5]);
          unsigned int y1 = pk2(sT[s][8 * kk + 6], sT[s][8 * kk + 7]);
          unsigned int sx0 = __shfl_xor(x0, 32), sy0 = __shfl_xor(y0, 32);
          unsigned int sx1 = __shfl_xor(x1, 32), sy1 = __shfl_xor(y1, 32);
          union { unsigned int u[4]; s16x8 v; } pf;
          pf.u[0] = hi ? sx1 : x0;
          pf.u[1] = hi ? sy1 : y0;
          pf.u[2] = hi ? x1 : sx0;
          pf.u[3] = hi ? y1 : sy0;
          __builtin_amdgcn_s_setprio(1);
#pragma unroll
          for (int dt = 0; dt < 2; ++dt) {
            s16x8 vf = *(const s16x8*)(vbase + (dt * 32 + l31) * 128 +
                                       ((c * 32 + hi * 16) ^ (l7 << 4)));
            accO[dt] = __builtin_amdgcn_mfma_f32_32x32x16_bf16(pf.v, vf, accO[dt], 0, 0, 0);
          }
          __builtin_amdgcn_s_setprio(0);
        }
      }

      // my prefetch landed + everyone done reading buf[cur]
      asm volatile("s_waitcnt vmcnt(0)" ::: "memory");
      __syncthreads();
      cur ^= 1;
    }

    // epilogue: O[q][d] with q = (r&3)+8*(r>>2)+4*hi, d = dt*32 + l31
    red[w][l31] = 1.0f / l_run;
#pragma unroll
    for (int r = 0; r < 16; ++r) {
      int R = (r & 3) + 8 * (r >> 2) + 4 * hi;
      float f = red[w][R];
      int qg = qw + R;
      size_t base = ((size_t)b * TQ_ + qg) * DM_ + h * DH_ + l31;
      Ob[base] = f2bf(accO[0][r] * f);
      Ob[base + 32] = f2bf(accO[1][r] * f);
    }
  }
#undef STAGE_KV
}

extern "C" void kernel_launch(void* const* d_in, const int* in_sizes, int n_in,
                              void* d_out, int out_size, void* d_ws, size_t ws_size,
                              hipStream_t stream) {
  const float* xq  = (const float*)d_in[0];
  const float* xkv = (const float*)d_in[1];
  const unsigned char* mask = (const unsigned char*)d_in[2];
  const float* Wq  = (const float*)d_in[3];
  const float* bq  = (const float*)d_in[4];
  const float* Wkv = (const float*)d_in[5];
  const float* bkv = (const float*)d_in[6];
  const float* Wo  = (const float*)d_in[7];
  const float* bo  = (const float*)d_in[8];
  const int* cflag = (const int*)d_in[9];
  float* out = (float*)d_out;

  char* ws = (char*)d_ws;
  unsigned short* WqT  = (unsigned short*)(ws);                       // 2 MiB
  unsigned short* WkvT = (unsigned short*)(ws + ((size_t)2 << 20));   // 4 MiB
  unsigned short* WoT  = (unsigned short*)(ws + ((size_t)6 << 20));   // 2 MiB
  unsigned short* Qb   = (unsigned short*)(ws + ((size_t)8 << 20));   // [B,H,TQ,64]
  unsigned short* Kb   = (unsigned short*)(ws + ((size_t)24 << 20));  // [B,H,TKV,64]
  unsigned short* Vb   = (unsigned short*)(ws + ((size_t)40 << 20));  // [B,H,64,TKV]
  unsigned short* Xr   = (unsigned short*)(ws + ((size_t)56 << 20));  // Aq -> Akv -> Ob
  unsigned short* Ob   = Xr;

  k_transpose_cast<<<dim3(16, 16), 256, 0, stream>>>(Wq, WqT, 1024, 1024, SC_FOLD);
  k_transpose_cast<<<dim3(32, 16), 256, 0, stream>>>(Wkv, WkvT, 1024, 2048, 1.0f);
  k_transpose_cast<<<dim3(16, 16), 256, 0, stream>>>(Wo, WoT, 1024, 1024, 1.0f);

  k_cast_bf16<<<2048, 256, 0, stream>>>(xq, Xr, B_ * TQ_ * DM_ / 4);
  k_gemm<0><<<dim3(8, 64), 256, 0, stream>>>(Xr, WqT, bq, SC_FOLD, Qb, nullptr, nullptr, 1024);

  k_cast_bf16<<<2048, 256, 0, stream>>>(xkv, Xr, B_ * TKV_ * DM_ / 4);
  k_gemm<1><<<dim3(16, 64), 256, 0, stream>>>(Xr, WkvT, bkv, 1.0f, Kb, Vb, nullptr, 1024);

  k_attn<<<dim3(8, B_ * H_), 256, 0, stream>>>(Qb, Kb, Vb, mask, cflag, Ob);

  k_gemm<2><<<dim3(8, 64), 256, 0, stream>>>(Ob, WoT, bo, 1.0f, nullptr, nullptr, out, 1024);
}

// Round 8
// 231.718 us; speedup vs baseline: 1.0723x; 1.0645x over previous
//
#include <hip/hip_runtime.h>
#include <hip/hip_bf16.h>

#define B_   4
#define TQ_  2048
#define TKV_ 2048
#define DM_  1024
#define H_   16
#define DH_  64

// 1/sqrt(DK) * log2(e), folded into Wq/bq so attention exp2 needs no scaling
#define SC_FOLD 0.18033688011112042f

using f32x4  = __attribute__((ext_vector_type(4))) float;
using f32x16 = __attribute__((ext_vector_type(16))) float;
using s16x8  = __attribute__((ext_vector_type(8))) short;

static __device__ __forceinline__ unsigned short f2bf(float f) {
  union { float f; unsigned int u; } v; v.f = f;
  unsigned int r = v.u + 0x7FFFu + ((v.u >> 16) & 1u);
  return (unsigned short)(r >> 16);
}
// packed f32 pair -> 2xbf16 (RNE) in one instruction
static __device__ __forceinline__ unsigned int pk2(float a, float b) {
  unsigned int r;
  asm("v_cvt_pk_bf16_f32 %0, %1, %2" : "=v"(r) : "v"(a), "v"(b));
  return r;
}
static __device__ __forceinline__ float max3f(float a, float b, float c) {
  float r;
  asm("v_max3_f32 %0, %1, %2, %3" : "=v"(r) : "v"(a), "v"(b), "v"(c));
  return r;
}

// async global->LDS, 16B per lane; LDS dest is wave-uniform base + lane*16
#define GL16(g, l)                                                          \
  __builtin_amdgcn_global_load_lds(                                         \
      (const __attribute__((address_space(1))) unsigned int*)(g),           \
      (__attribute__((address_space(3))) unsigned int*)(l), 16, 0, 0)

// ---------------- transpose + cast + scale: W[K][N] f32 -> WT[N][K] bf16 ----------------
__global__ __launch_bounds__(256) void k_transpose_cast(
    const float* __restrict__ W, unsigned short* __restrict__ WT, int K, int N,
    float scale) {
  __shared__ float t[64][65];
  int n0 = blockIdx.x * 64, k0 = blockIdx.y * 64;
  int tx = threadIdx.x & 63, ty = threadIdx.x >> 6;
#pragma unroll
  for (int i = 0; i < 64; i += 4)
    t[ty + i][tx] = W[(size_t)(k0 + ty + i) * N + n0 + tx];
  __syncthreads();
#pragma unroll
  for (int i = 0; i < 64; i += 4)
    WT[(size_t)(n0 + ty + i) * K + k0 + tx] = f2bf(t[tx][ty + i] * scale);
}

// ---------------- elementwise cast f32 -> bf16 ----------------
__global__ __launch_bounds__(256) void k_cast_bf16(
    const float* __restrict__ in, unsigned short* __restrict__ out, int n4) {
  for (int i = blockIdx.x * 256 + threadIdx.x; i < n4; i += gridDim.x * 256) {
    f32x4 v = *(const f32x4*)(in + (size_t)i * 4);
    unsigned long long u = (unsigned long long)pk2(v[0], v[1]) |
                           ((unsigned long long)pk2(v[2], v[3]) << 32);
    *(unsigned long long*)(out + (size_t)i * 4) = u;
  }
}

// ---------------- GEMM (m97 structure): C = A . BT^T + bias ----------------
template <int MODE>
__global__ __launch_bounds__(256) void k_gemm(
    const unsigned short* __restrict__ A, const unsigned short* __restrict__ BT,
    const float* __restrict__ bias, float bscale, unsigned short* __restrict__ out_a,
    unsigned short* __restrict__ out_b, float* __restrict__ out_f, int Kd) {
  __shared__ __align__(16) unsigned short As[128 * 32];
  __shared__ __align__(16) unsigned short Bs[128 * 32];
  int tid = threadIdx.x, lane = tid & 63, w = tid >> 6;
  int wm = w >> 1, wn = w & 1;

  int nwg = gridDim.x * gridDim.y;
  int bid = blockIdx.y * gridDim.x + blockIdx.x;
  int cpx = nwg >> 3;
  int sw = (bid & 7) * cpx + (bid >> 3);
  int bx = sw % gridDim.x, by = sw / gridDim.x;
  int m0 = by * 128, n0 = bx * 128;

  int srow = w * 32 + (lane >> 2);
  int scol = (lane & 3) * 8;
  const unsigned short* gA0 = A + (size_t)(m0 + srow) * Kd + scol;
  const unsigned short* gA1 = gA0 + (size_t)16 * Kd;
  const unsigned short* gB0 = BT + (size_t)(n0 + srow) * Kd + scol;
  const unsigned short* gB1 = gB0 + (size_t)16 * Kd;
  unsigned short* lA0 = As + w * 1024;
  unsigned short* lA1 = As + w * 1024 + 512;
  unsigned short* lB0 = Bs + w * 1024;
  unsigned short* lB1 = Bs + w * 1024 + 512;

  f32x4 acc[4][4];
#pragma unroll
  for (int i = 0; i < 4; ++i)
#pragma unroll
    for (int j = 0; j < 4; ++j) acc[i][j] = (f32x4){0.f, 0.f, 0.f, 0.f};

  for (int k0 = 0; k0 < Kd; k0 += 32) {
    __syncthreads();
    GL16(gA0 + k0, lA0);
    GL16(gA1 + k0, lA1);
    GL16(gB0 + k0, lB0);
    GL16(gB1 + k0, lB1);
    __syncthreads();

    s16x8 af[4], bf[4];
#pragma unroll
    for (int i = 0; i < 4; ++i) {
      af[i] = *(const s16x8*)(As + (wm * 64 + i * 16 + (lane & 15)) * 32 + (lane >> 4) * 8);
      bf[i] = *(const s16x8*)(Bs + (wn * 64 + i * 16 + (lane & 15)) * 32 + (lane >> 4) * 8);
    }
#pragma unroll
    for (int mi = 0; mi < 4; ++mi)
#pragma unroll
      for (int ni = 0; ni < 4; ++ni)
        acc[mi][ni] = __builtin_amdgcn_mfma_f32_16x16x32_bf16(af[mi], bf[ni], acc[mi][ni], 0, 0, 0);
  }

#pragma unroll
  for (int mi = 0; mi < 4; ++mi) {
#pragma unroll
    for (int ni = 0; ni < 4; ++ni) {
      int col = n0 + wn * 64 + ni * 16 + (lane & 15);
      int rbase = m0 + wm * 64 + mi * 16 + (lane >> 4) * 4;
      float bv = bias[col] * bscale;
      if (MODE == 1 && col >= H_ * DH_) {
        int c2 = col - H_ * DH_;
        int h = c2 >> 6, d = c2 & 63;
        int b = rbase >> 11, t = rbase & 2047;
        union { unsigned short h4[4]; unsigned long long u; } p;
#pragma unroll
        for (int r = 0; r < 4; ++r) p.h4[r] = f2bf(acc[mi][ni][r] + bv);
        *(unsigned long long*)(out_b + ((((size_t)b * H_ + h) * DH_ + d) * TKV_ + t)) = p.u;
      } else {
#pragma unroll
        for (int r = 0; r < 4; ++r) {
          float v = acc[mi][ni][r] + bv;
          int m = rbase + r;
          if (MODE == 0) {
            int b = m >> 11, t = m & 2047;
            int h = col >> 6, d = col & 63;
            out_a[(((size_t)b * H_ + h) * TQ_ + t) * DH_ + d] = f2bf(v);
          } else if (MODE == 1) {
            int b = m >> 11, t = m & 2047;
            int h = col >> 6, d = col & 63;
            out_a[(((size_t)b * H_ + h) * TKV_ + t) * DH_ + d] = f2bf(v);
          } else {
            out_f[(size_t)m * DM_ + col] = v;
          }
        }
      }
    }
  }
}

// ---------------- flash attention: R3 structure + T14 split staging + tree reductions ----
// grid (8, 64) x 256 threads = 4 waves x 32 q-rows; paired q-tiles (bx, 15-bx).
// Per tile: issue next-tile global loads into regs BEFORE compute; ds_write after
// the read-done barrier -> HBM latency hides under compute. Single LDS buffer.
__global__ __launch_bounds__(256, 3) void k_attn(
    const unsigned short* __restrict__ Qb, const unsigned short* __restrict__ Kb,
    const unsigned short* __restrict__ Vtb, const unsigned char* __restrict__ mask,
    const int* __restrict__ cflag, unsigned short* __restrict__ Ob) {
  __shared__ __align__(16) unsigned short Kt[64 * 64];  // [kv][d], XOR-swizzled
  __shared__ __align__(16) unsigned short Vt[64 * 64];  // [d][kv], XOR-swizzled
  __shared__ float bias_lds[64];
  __shared__ float red[4][32];
  __shared__ int s_any;

  // XCD head-locality swizzle: 8 q-blocks of a head on one XCD
  int bid = blockIdx.y * gridDim.x + blockIdx.x;
  int r8 = bid & 7, q8 = bid >> 3;
  int bh = r8 * 8 + (q8 >> 3);
  int bx = q8 & 7;

  int b = bh >> 4, h = bh & 15;
  int tid = threadIdx.x, lane = tid & 63, w = tid >> 6;
  int hi = lane >> 5, l31 = lane & 31, l7 = lane & 7;
  const unsigned short* Qp = Qb + (size_t)bh * TQ_ * DH_;
  const char* Kp = (const char*)(Kb + (size_t)bh * TKV_ * DH_);
  const char* Vp = (const char*)(Vtb + (size_t)bh * DH_ * TKV_);
  const unsigned char* mp = mask + (size_t)b * TKV_;
  int causal = cflag[0];
  char* kbase = (char*)Kt;
  char* vbase = (char*)Vt;

  // staging geometry: thread covers row st_row, bytes [cb, cb+16) for cb in {cb0, cb0+64}
  int st_row = tid >> 2;
  int st_cb0 = (tid & 3) * 16;
  s16x8 pKr[2], pVr[2];

#define LOAD_KV(kv0)                                                          \
  {                                                                           \
    _Pragma("unroll")                                                         \
    for (int p = 0; p < 2; ++p) {                                             \
      int cb = st_cb0 + p * 64;                                               \
      pKr[p] = *(const s16x8*)(Kp + ((size_t)((kv0) + st_row) * 128 + cb));   \
      pVr[p] = *(const s16x8*)(Vp + (((size_t)st_row * TKV_ + (kv0)) * 2 + cb)); \
    }                                                                         \
  }
#define WRITE_KV()                                                            \
  {                                                                           \
    _Pragma("unroll")                                                         \
    for (int p = 0; p < 2; ++p) {                                             \
      int cb = st_cb0 + p * 64;                                               \
      int sw = cb ^ ((st_row & 7) << 4);                                      \
      *(s16x8*)(kbase + st_row * 128 + sw) = pKr[p];                          \
      *(s16x8*)(vbase + st_row * 128 + sw) = pVr[p];                          \
    }                                                                         \
  }

  if (tid == 0) s_any = 0;
  __syncthreads();
  {
    int any = 0;
    for (int i = tid; i < TKV_; i += 256) any |= mp[i];
    if (any) s_any = 1;
  }
  __syncthreads();
  const int has_mask = s_any;

#pragma unroll 1
  for (int pass = 0; pass < 2; ++pass) {
    int qb = (pass ? (15 - bx) : bx) * 128;
    int qw = qb + w * 32;
    int qrow = qw + l31;

    s16x8 bQ[4];
#pragma unroll
    for (int kk = 0; kk < 4; ++kk)
      bQ[kk] = *(const s16x8*)(Qp + (size_t)qrow * DH_ + kk * 16 + hi * 8);

    f32x16 accO[2];
#pragma unroll
    for (int i = 0; i < 16; ++i) { accO[0][i] = 0.f; accO[1][i] = 0.f; }
    float m_run = -INFINITY, l_run = 0.f;

    int nT = (causal ? (qb + 128) : TKV_) >> 6;

    // prologue: stage tile 0
    LOAD_KV(0);
    WRITE_KV();
    if (has_mask && tid < 64) bias_lds[tid] = mp[tid] ? -1e30f : 0.0f;
    __syncthreads();

#pragma unroll 1
    for (int it = 0; it < nT; ++it) {
      int kv0 = it << 6;
      if (it + 1 < nT) LOAD_KV(kv0 + 64);  // async; lands during compute

      if (!(causal && kv0 >= qw + 32)) {
        // S^T = K . Q^T  (64 kv x 32 q per wave, two 32x32 sub-tiles)
        f32x16 sT[2];
#pragma unroll
        for (int i = 0; i < 16; ++i) { sT[0][i] = 0.f; sT[1][i] = 0.f; }
        __builtin_amdgcn_s_setprio(1);
#pragma unroll
        for (int s = 0; s < 2; ++s) {
#pragma unroll
          for (int kk = 0; kk < 4; ++kk) {
            s16x8 aK = *(const s16x8*)(kbase + (s * 32 + l31) * 128 +
                                       ((kk * 32 + hi * 16) ^ (l7 << 4)));
            sT[s] = __builtin_amdgcn_mfma_f32_32x32x16_bf16(aK, bQ[kk], sT[s], 0, 0, 0);
          }
        }
        __builtin_amdgcn_s_setprio(0);

        int diag = causal && (kv0 + 64 > qw);  // wave-uniform
        float a0, a1, a2, a3;
        if (diag || has_mask) {
#pragma unroll
          for (int s = 0; s < 2; ++s)
#pragma unroll
            for (int r = 0; r < 16; ++r) {
              int kvloc = s * 32 + (r & 3) + 8 * (r >> 2) + 4 * hi;
              float sv = sT[s][r];
              if (has_mask) sv += bias_lds[kvloc];
              if (diag && (kv0 + kvloc) > qrow) sv = -1e30f;
              sT[s][r] = sv;
            }
        }
        // row-max via 4 parallel accumulators (chain len 8) + max3 combine
        a0 = sT[0][0]; a1 = sT[0][1]; a2 = sT[0][2]; a3 = sT[0][3];
#pragma unroll
        for (int r = 4; r < 16; r += 4) {
          a0 = fmaxf(a0, sT[0][r + 0]); a1 = fmaxf(a1, sT[0][r + 1]);
          a2 = fmaxf(a2, sT[0][r + 2]); a3 = fmaxf(a3, sT[0][r + 3]);
        }
#pragma unroll
        for (int r = 0; r < 16; r += 4) {
          a0 = fmaxf(a0, sT[1][r + 0]); a1 = fmaxf(a1, sT[1][r + 1]);
          a2 = fmaxf(a2, sT[1][r + 2]); a3 = fmaxf(a3, sT[1][r + 3]);
        }
        float mx = max3f(max3f(a0, a1, a2), a3, -3.0e30f);
        mx = fmaxf(mx, __shfl_xor(mx, 32));

        // T13 defer-rescale
        if (!__all(mx - m_run <= 8.0f)) {
          float mnew = fmaxf(m_run, mx);
          float sc_o = exp2f(m_run - mnew);
          m_run = mnew;
          l_run *= sc_o;
          red[w][l31] = sc_o;
#pragma unroll
          for (int r = 0; r < 16; ++r) {
            float f = red[w][(r & 3) + 8 * (r >> 2) + 4 * hi];
            accO[0][r] *= f;
            accO[1][r] *= f;
          }
        }

        // exp + 4-way parallel partial sums
        float s0acc = 0.f, s1acc = 0.f, s2acc = 0.f, s3acc = 0.f;
#pragma unroll
        for (int s = 0; s < 2; ++s)
#pragma unroll
          for (int r = 0; r < 16; r += 4) {
            float p0 = exp2f(sT[s][r + 0] - m_run);
            float p1 = exp2f(sT[s][r + 1] - m_run);
            float p2 = exp2f(sT[s][r + 2] - m_run);
            float p3 = exp2f(sT[s][r + 3] - m_run);
            sT[s][r + 0] = p0; sT[s][r + 1] = p1;
            sT[s][r + 2] = p2; sT[s][r + 3] = p3;
            s0acc += p0; s1acc += p1; s2acc += p2; s3acc += p3;
          }
        float ls = (s0acc + s1acc) + (s2acc + s3acc);
        ls += __shfl_xor(ls, 32);
        l_run += ls;

        // P -> A-frag (cvt_pk + 4 shfl per k-chunk) + PV
#pragma unroll
        for (int c = 0; c < 4; ++c) {
          int s = c >> 1, kk = c & 1;
          unsigned int x0 = pk2(sT[s][8 * kk + 0], sT[s][8 * kk + 1]);
          unsigned int y0 = pk2(sT[s][8 * kk + 2], sT[s][8 * kk + 3]);
          unsigned int x1 = pk2(sT[s][8 * kk + 4], sT[s][8 * kk + 5]);
          unsigned int y1 = pk2(sT[s][8 * kk + 6], sT[s][8 * kk + 7]);
          unsigned int sx0 = __shfl_xor(x0, 32), sy0 = __shfl_xor(y0, 32);
          unsigned int sx1 = __shfl_xor(x1, 32), sy1 = __shfl_xor(y1, 32);
          union { unsigned int u[4]; s16x8 v; } pf;
          pf.u[0] = hi ? sx1 : x0;
          pf.u[1] = hi ? sy1 : y0;
          pf.u[2] = hi ? x1 : sx0;
          pf.u[3] = hi ? y1 : sy0;
          __builtin_amdgcn_s_setprio(1);
#pragma unroll
          for (int dt = 0; dt < 2; ++dt) {
            s16x8 vf = *(const s16x8*)(vbase + (dt * 32 + l31) * 128 +
                                       ((c * 32 + hi * 16) ^ (l7 << 4)));
            accO[dt] = __builtin_amdgcn_mfma_f32_32x32x16_bf16(pf.v, vf, accO[dt], 0, 0, 0);
          }
          __builtin_amdgcn_s_setprio(0);
        }
      }

      __syncthreads();  // everyone done reading tile it
      if (it + 1 < nT) {
        WRITE_KV();     // compiler waits vmcnt for pKr/pVr
        if (has_mask && tid < 64) bias_lds[tid] = mp[kv0 + 64 + tid] ? -1e30f : 0.0f;
      }
      __syncthreads();  // writes visible
    }

    // epilogue: O[q][d] with q = (r&3)+8*(r>>2)+4*hi, d = dt*32 + l31
    red[w][l31] = 1.0f / l_run;
#pragma unroll
    for (int r = 0; r < 16; ++r) {
      int R = (r & 3) + 8 * (r >> 2) + 4 * hi;
      float f = red[w][R];
      int qg = qw + R;
      size_t base = ((size_t)b * TQ_ + qg) * DM_ + h * DH_ + l31;
      Ob[base] = f2bf(accO[0][r] * f);
      Ob[base + 32] = f2bf(accO[1][r] * f);
    }
  }
#undef LOAD_KV
#undef WRITE_KV
}

extern "C" void kernel_launch(void* const* d_in, const int* in_sizes, int n_in,
                              void* d_out, int out_size, void* d_ws, size_t ws_size,
                              hipStream_t stream) {
  const float* xq  = (const float*)d_in[0];
  const float* xkv = (const float*)d_in[1];
  const unsigned char* mask = (const unsigned char*)d_in[2];
  const float* Wq  = (const float*)d_in[3];
  const float* bq  = (const float*)d_in[4];
  const float* Wkv = (const float*)d_in[5];
  const float* bkv = (const float*)d_in[6];
  const float* Wo  = (const float*)d_in[7];
  const float* bo  = (const float*)d_in[8];
  const int* cflag = (const int*)d_in[9];
  float* out = (float*)d_out;

  char* ws = (char*)d_ws;
  unsigned short* WqT  = (unsigned short*)(ws);                       // 2 MiB
  unsigned short* WkvT = (unsigned short*)(ws + ((size_t)2 << 20));   // 4 MiB
  unsigned short* WoT  = (unsigned short*)(ws + ((size_t)6 << 20));   // 2 MiB
  unsigned short* Qb   = (unsigned short*)(ws + ((size_t)8 << 20));   // [B,H,TQ,64]
  unsigned short* Kb   = (unsigned short*)(ws + ((size_t)24 << 20));  // [B,H,TKV,64]
  unsigned short* Vb   = (unsigned short*)(ws + ((size_t)40 << 20));  // [B,H,64,TKV]
  unsigned short* Xr   = (unsigned short*)(ws + ((size_t)56 << 20));  // Aq -> Akv -> Ob
  unsigned short* Ob   = Xr;

  k_transpose_cast<<<dim3(16, 16), 256, 0, stream>>>(Wq, WqT, 1024, 1024, SC_FOLD);
  k_transpose_cast<<<dim3(32, 16), 256, 0, stream>>>(Wkv, WkvT, 1024, 2048, 1.0f);
  k_transpose_cast<<<dim3(16, 16), 256, 0, stream>>>(Wo, WoT, 1024, 1024, 1.0f);

  k_cast_bf16<<<2048, 256, 0, stream>>>(xq, Xr, B_ * TQ_ * DM_ / 4);
  k_gemm<0><<<dim3(8, 64), 256, 0, stream>>>(Xr, WqT, bq, SC_FOLD, Qb, nullptr, nullptr, 1024);

  k_cast_bf16<<<2048, 256, 0, stream>>>(xkv, Xr, B_ * TKV_ * DM_ / 4);
  k_gemm<1><<<dim3(16, 64), 256, 0, stream>>>(Xr, WkvT, bkv, 1.0f, Kb, Vb, nullptr, 1024);

  k_attn<<<dim3(8, B_ * H_), 256, 0, stream>>>(Qb, Kb, Vb, mask, cflag, Ob);

  k_gemm<2><<<dim3(8, 64), 256, 0, stream>>>(Ob, WoT, bo, 1.0f, nullptr, nullptr, out, 1024);
}

// Round 10
// 207.941 us; speedup vs baseline: 1.1949x; 1.1143x over previous
//
#include <hip/hip_runtime.h>
#include <hip/hip_bf16.h>

#define B_   4
#define TQ_  2048
#define TKV_ 2048
#define DM_  1024
#define H_   16
#define DH_  64

// 1/sqrt(DK) * log2(e), folded into Wq/bq so attention exp2 needs no scaling
#define SC_FOLD 0.18033688011112042f

using f32x4  = __attribute__((ext_vector_type(4))) float;
using f32x16 = __attribute__((ext_vector_type(16))) float;
using s16x8  = __attribute__((ext_vector_type(8))) short;

static __device__ __forceinline__ unsigned short f2bf(float f) {
  union { float f; unsigned int u; } v; v.f = f;
  unsigned int r = v.u + 0x7FFFu + ((v.u >> 16) & 1u);
  return (unsigned short)(r >> 16);
}
// packed f32 pair -> 2xbf16 (RNE) in one instruction
static __device__ __forceinline__ unsigned int pk2(float a, float b) {
  unsigned int r;
  asm("v_cvt_pk_bf16_f32 %0, %1, %2" : "=v"(r) : "v"(a), "v"(b));
  return r;
}
static __device__ __forceinline__ float max3f(float a, float b, float c) {
  float r;
  asm("v_max3_f32 %0, %1, %2, %3" : "=v"(r) : "v"(a), "v"(b), "v"(c));
  return r;
}

// async global->LDS, 16B per lane; LDS dest is wave-uniform base + lane*16
#define GL16(g, l)                                                          \
  __builtin_amdgcn_global_load_lds(                                         \
      (const __attribute__((address_space(1))) unsigned int*)(g),           \
      (__attribute__((address_space(3))) unsigned int*)(l), 16, 0, 0)

// ---------------- transpose + cast + scale: W[K][N] f32 -> WT[N][K] bf16 ----------------
__global__ __launch_bounds__(256) void k_transpose_cast(
    const float* __restrict__ W, unsigned short* __restrict__ WT, int K, int N,
    float scale) {
  __shared__ float t[64][65];
  int n0 = blockIdx.x * 64, k0 = blockIdx.y * 64;
  int tx = threadIdx.x & 63, ty = threadIdx.x >> 6;
#pragma unroll
  for (int i = 0; i < 64; i += 4)
    t[ty + i][tx] = W[(size_t)(k0 + ty + i) * N + n0 + tx];
  __syncthreads();
#pragma unroll
  for (int i = 0; i < 64; i += 4)
    WT[(size_t)(n0 + ty + i) * K + k0 + tx] = f2bf(t[tx][ty + i] * scale);
}

// ---------------- elementwise cast f32 -> bf16 ----------------
__global__ __launch_bounds__(256) void k_cast_bf16(
    const float* __restrict__ in, unsigned short* __restrict__ out, int n4) {
  for (int i = blockIdx.x * 256 + threadIdx.x; i < n4; i += gridDim.x * 256) {
    f32x4 v = *(const f32x4*)(in + (size_t)i * 4);
    unsigned long long u = (unsigned long long)pk2(v[0], v[1]) |
                           ((unsigned long long)pk2(v[2], v[3]) << 32);
    *(unsigned long long*)(out + (size_t)i * 4) = u;
  }
}

// ---------------- GEMM, 8-phase 256-row tile (T1+T2+T3+T4+T5) ----------------
// C = A . BT^T + bias. A bf16 [M][Kd], BT bf16 [N][Kd]. BM=256, BK=64,
// 512 threads = 8 waves (2M x 4N); per-wave output 128 x (BN/4).
// 16x16x32 MFMA fragments. Chunk = 64 rows x 128B staged by one GL16/thread.
// Raw s_barrier + counted vmcnt (never 0 mid-loop); LDS XOR-swizzle via
// pre-swizzled global source (rule #21).
// MODE 0: write Q [B,H,T,64] bf16
// MODE 1: write K [B,H,T,64] bf16, V TRANSPOSED [B,H,64,TKV] bf16
// MODE 2: write fp32 out [m][n]
template <int MODE, int BN>
__global__ __launch_bounds__(512, 2) void k_gemm8(
    const unsigned short* __restrict__ A, const unsigned short* __restrict__ BT,
    const float* __restrict__ bias, float bscale, unsigned short* __restrict__ out_a,
    unsigned short* __restrict__ out_b, float* __restrict__ out_f, int Kd) {
  constexpr int NI = BN / 64;   // n-frags per wave: 4 (BN=256) or 2 (BN=128)
  constexpr int NH = NI / 2;    // n-frags per phase
  __shared__ __align__(16) unsigned short As[2 * 256 * 64];
  __shared__ __align__(16) unsigned short Bs[2 * BN * 64];
  const int tid = threadIdx.x, lane = tid & 63, w = tid >> 6;
  const int wm = w >> 2, wn = w & 3;

  // T1 bijective XCD swizzle (nwg = 256 for all our grids)
  int nwg = gridDim.x * gridDim.y;
  int bid = blockIdx.y * gridDim.x + blockIdx.x;
  int cpx = nwg >> 3;
  int sw = (bid & 7) * cpx + (bid >> 3);
  int bx = sw % gridDim.x, by = sw / gridDim.x;
  int m0 = by * 256, n0 = bx * BN;

  // staging geometry: thread covers chunk row tid>>3, 16B at pre-swizzled sx
  const int strow = tid >> 3;
  const int sx = ((tid & 7) << 4) ^ ((strow & 7) << 4);
  const char* gA = (const char*)(A + (size_t)(m0 + strow) * Kd) + sx;
  const char* gB = (const char*)(BT + (size_t)(n0 + strow) * Kd) + sx;
  char* lA = (char*)As;
  char* lB = (char*)Bs;

#define ST_A(bf, c, k0) \
  GL16(gA + ((size_t)(c) * 64 * Kd + (size_t)(k0)) * 2, lA + (bf) * 32768 + (c) * 8192 + tid * 16)
#define ST_B(bf, c, k0) \
  GL16(gB + ((size_t)(c) * 64 * Kd + (size_t)(k0)) * 2, lB + (bf) * (BN * 128) + (c) * 8192 + tid * 16)

  f32x4 acc[8][NI];
#pragma unroll
  for (int i = 0; i < 8; ++i)
#pragma unroll
    for (int j = 0; j < NI; ++j) acc[i][j] = (f32x4){0.f, 0.f, 0.f, 0.f};

  s16x8 afr[4][2], bfr[NI][2];
  const int arow = wm * 128 + (lane & 15);        // + mi*16
  const int brow = wn * (NI * 16) + (lane & 15);  // + ni*16
  const int fcol = (lane >> 4) * 16;              // + kk*64

#define RD_A(bf, r) (*(const s16x8*)(lA + (bf) * 32768 + (r) * 128 + ((fcol + _kk * 64) ^ (((r) & 7) << 4))))
#define RD_B(bf, r) (*(const s16x8*)(lB + (bf) * (BN * 128) + (r) * 128 + ((fcol + _kk * 64) ^ (((r) & 7) << 4))))

  const int nT = Kd >> 6;

  // prologue: stage tile 0 (chunk order matches steady state: needed-first)
  ST_B(0, 0, 0); ST_B(0, 1, 0);
  if (BN == 256) { ST_B(0, 2, 0); ST_B(0, 3, 0); }
  ST_A(0, 0, 0); ST_A(0, 2, 0);
  ST_A(0, 1, 0); ST_A(0, 3, 0);
  asm volatile("s_waitcnt vmcnt(2)" ::: "memory");
  __builtin_amdgcn_s_barrier();

#pragma unroll 1
  for (int t = 0; t < nT; ++t) {
    const int cur = t & 1, nxt = cur ^ 1;
    const int k1 = (t + 1) << 6;
    const bool st = (t + 1 < nT);

    // ---- phase 1: ds_read A(mi0-3) + B(ni<NH); stage B chunks 0,1 ----
#pragma unroll
    for (int mi = 0; mi < 4; ++mi)
#pragma unroll
      for (int _kk = 0; _kk < 2; ++_kk) afr[mi][_kk] = RD_A(cur, arow + mi * 16);
#pragma unroll
    for (int ni = 0; ni < NH; ++ni)
#pragma unroll
      for (int _kk = 0; _kk < 2; ++_kk) bfr[ni][_kk] = RD_B(cur, brow + ni * 16);
    if (st) { ST_B(nxt, 0, k1); ST_B(nxt, 1, k1); }
    __builtin_amdgcn_s_barrier();
    __builtin_amdgcn_s_setprio(1);
#pragma unroll
    for (int mi = 0; mi < 4; ++mi)
#pragma unroll
      for (int ni = 0; ni < NH; ++ni)
#pragma unroll
        for (int kk = 0; kk < 2; ++kk)
          acc[mi][ni] = __builtin_amdgcn_mfma_f32_16x16x32_bf16(afr[mi][kk], bfr[ni][kk], acc[mi][ni], 0, 0, 0);
    __builtin_amdgcn_s_setprio(0);
    __builtin_amdgcn_s_barrier();

    // ---- phase 2: ds_read B(ni>=NH); stage {B23 | A02} ----
#pragma unroll
    for (int ni = NH; ni < NI; ++ni)
#pragma unroll
      for (int _kk = 0; _kk < 2; ++_kk) bfr[ni][_kk] = RD_B(cur, brow + ni * 16);
    if (st) {
      if (BN == 256) { ST_B(nxt, 2, k1); ST_B(nxt, 3, k1); }
      else           { ST_A(nxt, 0, k1); ST_A(nxt, 2, k1); }
    }
    if (st) asm volatile("s_waitcnt vmcnt(4)" ::: "memory");
    else    asm volatile("s_waitcnt vmcnt(0)" ::: "memory");
    __builtin_amdgcn_s_barrier();
    __builtin_amdgcn_s_setprio(1);
#pragma unroll
    for (int mi = 0; mi < 4; ++mi)
#pragma unroll
      for (int ni = NH; ni < NI; ++ni)
#pragma unroll
        for (int kk = 0; kk < 2; ++kk)
          acc[mi][ni] = __builtin_amdgcn_mfma_f32_16x16x32_bf16(afr[mi][kk], bfr[ni][kk], acc[mi][ni], 0, 0, 0);
    __builtin_amdgcn_s_setprio(0);
    __builtin_amdgcn_s_barrier();

    // ---- phase 3: ds_read A(mi4-7); stage {A02 | A13} ----
#pragma unroll
    for (int mi = 0; mi < 4; ++mi)
#pragma unroll
      for (int _kk = 0; _kk < 2; ++_kk) afr[mi][_kk] = RD_A(cur, arow + (mi + 4) * 16);
    if (st) {
      if (BN == 256) { ST_A(nxt, 0, k1); ST_A(nxt, 2, k1); }
      else           { ST_A(nxt, 1, k1); ST_A(nxt, 3, k1); }
    }
    __builtin_amdgcn_s_barrier();
    __builtin_amdgcn_s_setprio(1);
#pragma unroll
    for (int mi = 0; mi < 4; ++mi)
#pragma unroll
      for (int ni = 0; ni < NH; ++ni)
#pragma unroll
        for (int kk = 0; kk < 2; ++kk)
          acc[mi + 4][ni] = __builtin_amdgcn_mfma_f32_16x16x32_bf16(afr[mi][kk], bfr[ni][kk], acc[mi + 4][ni], 0, 0, 0);
    __builtin_amdgcn_s_setprio(0);
    __builtin_amdgcn_s_barrier();

    // ---- phase 4: stage {A13 | -}; counted vmcnt for next tile's phase 1 ----
    if (st && BN == 256) { ST_A(nxt, 1, k1); ST_A(nxt, 3, k1); }
    asm volatile("s_waitcnt vmcnt(2)" ::: "memory");
    __builtin_amdgcn_s_barrier();
    __builtin_amdgcn_s_setprio(1);
#pragma unroll
    for (int mi = 0; mi < 4; ++mi)
#pragma unroll
      for (int ni = NH; ni < NI; ++ni)
#pragma unroll
        for (int kk = 0; kk < 2; ++kk)
          acc[mi + 4][ni] = __builtin_amdgcn_mfma_f32_16x16x32_bf16(afr[mi][kk], bfr[ni][kk], acc[mi + 4][ni], 0, 0, 0);
    __builtin_amdgcn_s_setprio(0);
    __builtin_amdgcn_s_barrier();
  }

  // ---- epilogue ----
#pragma unroll
  for (int mi = 0; mi < 8; ++mi) {
#pragma unroll
    for (int ni = 0; ni < NI; ++ni) {
      int col = n0 + wn * (NI * 16) + ni * 16 + (lane & 15);
      int rbase = m0 + wm * 128 + mi * 16 + (lane >> 4) * 4;
      float bv = bias[col] * bscale;
      if (MODE == 1 && col >= H_ * DH_) {
        int c2 = col - H_ * DH_;
        int h = c2 >> 6, d = c2 & 63;
        int b = rbase >> 11, tt = rbase & 2047;
        union { unsigned short h4[4]; unsigned long long u; } p;
#pragma unroll
        for (int r = 0; r < 4; ++r) p.h4[r] = f2bf(acc[mi][ni][r] + bv);
        *(unsigned long long*)(out_b + ((((size_t)b * H_ + h) * DH_ + d) * TKV_ + tt)) = p.u;
      } else {
#pragma unroll
        for (int r = 0; r < 4; ++r) {
          float v = acc[mi][ni][r] + bv;
          int m = rbase + r;
          if (MODE == 0) {
            int b = m >> 11, tt = m & 2047;
            int h = col >> 6, d = col & 63;
            out_a[(((size_t)b * H_ + h) * TQ_ + tt) * DH_ + d] = f2bf(v);
          } else if (MODE == 1) {
            int b = m >> 11, tt = m & 2047;
            int h = col >> 6, d = col & 63;
            out_a[(((size_t)b * H_ + h) * TKV_ + tt) * DH_ + d] = f2bf(v);
          } else {
            out_f[(size_t)m * DM_ + col] = v;
          }
        }
      }
    }
  }
#undef ST_A
#undef ST_B
#undef RD_A
#undef RD_B
}

// ---------------- flash attention (unchanged from R7: 97 µs plateau) ----------------
__global__ __launch_bounds__(256, 3) void k_attn(
    const unsigned short* __restrict__ Qb, const unsigned short* __restrict__ Kb,
    const unsigned short* __restrict__ Vtb, const unsigned char* __restrict__ mask,
    const int* __restrict__ cflag, unsigned short* __restrict__ Ob) {
  __shared__ __align__(16) unsigned short Kt[64 * 64];  // [kv][d], XOR-swizzled
  __shared__ __align__(16) unsigned short Vt[64 * 64];  // [d][kv], XOR-swizzled
  __shared__ float bias_lds[64];
  __shared__ float red[4][32];
  __shared__ int s_any;

  int bid = blockIdx.y * gridDim.x + blockIdx.x;
  int r8 = bid & 7, q8 = bid >> 3;
  int bh = r8 * 8 + (q8 >> 3);
  int bx = q8 & 7;

  int b = bh >> 4, h = bh & 15;
  int tid = threadIdx.x, lane = tid & 63, w = tid >> 6;
  int hi = lane >> 5, l31 = lane & 31, l7 = lane & 7;
  const unsigned short* Qp = Qb + (size_t)bh * TQ_ * DH_;
  const char* Kp = (const char*)(Kb + (size_t)bh * TKV_ * DH_);
  const char* Vp = (const char*)(Vtb + (size_t)bh * DH_ * TKV_);
  const unsigned char* mp = mask + (size_t)b * TKV_;
  int causal = cflag[0];
  char* kbase = (char*)Kt;
  char* vbase = (char*)Vt;

  int st_row = tid >> 2;
  int st_cb0 = (tid & 3) * 16;
  s16x8 pKr[2], pVr[2];

#define LOAD_KV(kv0)                                                          \
  {                                                                           \
    _Pragma("unroll")                                                         \
    for (int p = 0; p < 2; ++p) {                                             \
      int cb = st_cb0 + p * 64;                                               \
      pKr[p] = *(const s16x8*)(Kp + ((size_t)((kv0) + st_row) * 128 + cb));   \
      pVr[p] = *(const s16x8*)(Vp + (((size_t)st_row * TKV_ + (kv0)) * 2 + cb)); \
    }                                                                         \
  }
#define WRITE_KV()                                                            \
  {                                                                           \
    _Pragma("unroll")                                                         \
    for (int p = 0; p < 2; ++p) {                                             \
      int cb = st_cb0 + p * 64;                                               \
      int sw = cb ^ ((st_row & 7) << 4);                                      \
      *(s16x8*)(kbase + st_row * 128 + sw) = pKr[p];                          \
      *(s16x8*)(vbase + st_row * 128 + sw) = pVr[p];                          \
    }                                                                         \
  }

  if (tid == 0) s_any = 0;
  __syncthreads();
  {
    int any = 0;
    for (int i = tid; i < TKV_; i += 256) any |= mp[i];
    if (any) s_any = 1;
  }
  __syncthreads();
  const int has_mask = s_any;

#pragma unroll 1
  for (int pass = 0; pass < 2; ++pass) {
    int qb = (pass ? (15 - bx) : bx) * 128;
    int qw = qb + w * 32;
    int qrow = qw + l31;

    s16x8 bQ[4];
#pragma unroll
    for (int kk = 0; kk < 4; ++kk)
      bQ[kk] = *(const s16x8*)(Qp + (size_t)qrow * DH_ + kk * 16 + hi * 8);

    f32x16 accO[2];
#pragma unroll
    for (int i = 0; i < 16; ++i) { accO[0][i] = 0.f; accO[1][i] = 0.f; }
    float m_run = -INFINITY, l_run = 0.f;

    int nT = (causal ? (qb + 128) : TKV_) >> 6;

    LOAD_KV(0);
    WRITE_KV();
    if (has_mask && tid < 64) bias_lds[tid] = mp[tid] ? -1e30f : 0.0f;
    __syncthreads();

#pragma unroll 1
    for (int it = 0; it < nT; ++it) {
      int kv0 = it << 6;
      if (it + 1 < nT) LOAD_KV(kv0 + 64);

      if (!(causal && kv0 >= qw + 32)) {
        f32x16 sT[2];
#pragma unroll
        for (int i = 0; i < 16; ++i) { sT[0][i] = 0.f; sT[1][i] = 0.f; }
        __builtin_amdgcn_s_setprio(1);
#pragma unroll
        for (int s = 0; s < 2; ++s) {
#pragma unroll
          for (int kk = 0; kk < 4; ++kk) {
            s16x8 aK = *(const s16x8*)(kbase + (s * 32 + l31) * 128 +
                                       ((kk * 32 + hi * 16) ^ (l7 << 4)));
            sT[s] = __builtin_amdgcn_mfma_f32_32x32x16_bf16(aK, bQ[kk], sT[s], 0, 0, 0);
          }
        }
        __builtin_amdgcn_s_setprio(0);

        int diag = causal && (kv0 + 64 > qw);
        float a0, a1, a2, a3;
        if (diag || has_mask) {
#pragma unroll
          for (int s = 0; s < 2; ++s)
#pragma unroll
            for (int r = 0; r < 16; ++r) {
              int kvloc = s * 32 + (r & 3) + 8 * (r >> 2) + 4 * hi;
              float sv = sT[s][r];
              if (has_mask) sv += bias_lds[kvloc];
              if (diag && (kv0 + kvloc) > qrow) sv = -1e30f;
              sT[s][r] = sv;
            }
        }
        a0 = sT[0][0]; a1 = sT[0][1]; a2 = sT[0][2]; a3 = sT[0][3];
#pragma unroll
        for (int r = 4; r < 16; r += 4) {
          a0 = fmaxf(a0, sT[0][r + 0]); a1 = fmaxf(a1, sT[0][r + 1]);
          a2 = fmaxf(a2, sT[0][r + 2]); a3 = fmaxf(a3, sT[0][r + 3]);
        }
#pragma unroll
        for (int r = 0; r < 16; r += 4) {
          a0 = fmaxf(a0, sT[1][r + 0]); a1 = fmaxf(a1, sT[1][r + 1]);
          a2 = fmaxf(a2, sT[1][r + 2]); a3 = fmaxf(a3, sT[1][r + 3]);
        }
        float mx = max3f(max3f(a0, a1, a2), a3, -3.0e30f);
        mx = fmaxf(mx, __shfl_xor(mx, 32));

        if (!__all(mx - m_run <= 8.0f)) {
          float mnew = fmaxf(m_run, mx);
          float sc_o = exp2f(m_run - mnew);
          m_run = mnew;
          l_run *= sc_o;
          red[w][l31] = sc_o;
#pragma unroll
          for (int r = 0; r < 16; ++r) {
            float f = red[w][(r & 3) + 8 * (r >> 2) + 4 * hi];
            accO[0][r] *= f;
            accO[1][r] *= f;
          }
        }

        float s0acc = 0.f, s1acc = 0.f, s2acc = 0.f, s3acc = 0.f;
#pragma unroll
        for (int s = 0; s < 2; ++s)
#pragma unroll
          for (int r = 0; r < 16; r += 4) {
            float p0 = exp2f(sT[s][r + 0] - m_run);
            float p1 = exp2f(sT[s][r + 1] - m_run);
            float p2 = exp2f(sT[s][r + 2] - m_run);
            float p3 = exp2f(sT[s][r + 3] - m_run);
            sT[s][r + 0] = p0; sT[s][r + 1] = p1;
            sT[s][r + 2] = p2; sT[s][r + 3] = p3;
            s0acc += p0; s1acc += p1; s2acc += p2; s3acc += p3;
          }
        float ls = (s0acc + s1acc) + (s2acc + s3acc);
        ls += __shfl_xor(ls, 32);
        l_run += ls;

#pragma unroll
        for (int c = 0; c < 4; ++c) {
          int s = c >> 1, kk = c & 1;
          unsigned int x0 = pk2(sT[s][8 * kk + 0], sT[s][8 * kk + 1]);
          unsigned int y0 = pk2(sT[s][8 * kk + 2], sT[s][8 * kk + 3]);
          unsigned int x1 = pk2(sT[s][8 * kk + 4], sT[s][8 * kk + 5]);
          unsigned int y1 = pk2(sT[s][8 * kk + 6], sT[s][8 * kk + 7]);
          unsigned int sx0 = __shfl_xor(x0, 32), sy0 = __shfl_xor(y0, 32);
          unsigned int sx1 = __shfl_xor(x1, 32), sy1 = __shfl_xor(y1, 32);
          union { unsigned int u[4]; s16x8 v; } pf;
          pf.u[0] = hi ? sx1 : x0;
          pf.u[1] = hi ? sy1 : y0;
          pf.u[2] = hi ? x1 : sx0;
          pf.u[3] = hi ? y1 : sy0;
          __builtin_amdgcn_s_setprio(1);
#pragma unroll
          for (int dt = 0; dt < 2; ++dt) {
            s16x8 vf = *(const s16x8*)(vbase + (dt * 32 + l31) * 128 +
                                       ((c * 32 + hi * 16) ^ (l7 << 4)));
            accO[dt] = __builtin_amdgcn_mfma_f32_32x32x16_bf16(pf.v, vf, accO[dt], 0, 0, 0);
          }
          __builtin_amdgcn_s_setprio(0);
        }
      }

      __syncthreads();
      if (it + 1 < nT) {
        WRITE_KV();
        if (has_mask && tid < 64) bias_lds[tid] = mp[kv0 + 64 + tid] ? -1e30f : 0.0f;
      }
      __syncthreads();
    }

    red[w][l31] = 1.0f / l_run;
#pragma unroll
    for (int r = 0; r < 16; ++r) {
      int R = (r & 3) + 8 * (r >> 2) + 4 * hi;
      float f = red[w][R];
      int qg = qw + R;
      size_t base = ((size_t)b * TQ_ + qg) * DM_ + h * DH_ + l31;
      Ob[base] = f2bf(accO[0][r] * f);
      Ob[base + 32] = f2bf(accO[1][r] * f);
    }
  }
#undef LOAD_KV
#undef WRITE_KV
}

extern "C" void kernel_launch(void* const* d_in, const int* in_sizes, int n_in,
                              void* d_out, int out_size, void* d_ws, size_t ws_size,
                              hipStream_t stream) {
  const float* xq  = (const float*)d_in[0];
  const float* xkv = (const float*)d_in[1];
  const unsigned char* mask = (const unsigned char*)d_in[2];
  const float* Wq  = (const float*)d_in[3];
  const float* bq  = (const float*)d_in[4];
  const float* Wkv = (const float*)d_in[5];
  const float* bkv = (const float*)d_in[6];
  const float* Wo  = (const float*)d_in[7];
  const float* bo  = (const float*)d_in[8];
  const int* cflag = (const int*)d_in[9];
  float* out = (float*)d_out;

  char* ws = (char*)d_ws;
  unsigned short* WqT  = (unsigned short*)(ws);                       // 2 MiB
  unsigned short* WkvT = (unsigned short*)(ws + ((size_t)2 << 20));   // 4 MiB
  unsigned short* WoT  = (unsigned short*)(ws + ((size_t)6 << 20));   // 2 MiB
  unsigned short* Qb   = (unsigned short*)(ws + ((size_t)8 << 20));   // [B,H,TQ,64]
  unsigned short* Kb   = (unsigned short*)(ws + ((size_t)24 << 20));  // [B,H,TKV,64]
  unsigned short* Vb   = (unsigned short*)(ws + ((size_t)40 << 20));  // [B,H,64,TKV]
  unsigned short* Xr   = (unsigned short*)(ws + ((size_t)56 << 20));  // Aq -> Akv -> Ob
  unsigned short* Ob   = Xr;

  k_transpose_cast<<<dim3(16, 16), 256, 0, stream>>>(Wq, WqT, 1024, 1024, SC_FOLD);
  k_transpose_cast<<<dim3(32, 16), 256, 0, stream>>>(Wkv, WkvT, 1024, 2048, 1.0f);
  k_transpose_cast<<<dim3(16, 16), 256, 0, stream>>>(Wo, WoT, 1024, 1024, 1.0f);

  k_cast_bf16<<<2048, 256, 0, stream>>>(xq, Xr, B_ * TQ_ * DM_ / 4);
  k_gemm8<0, 128><<<dim3(8, 32), 512, 0, stream>>>(Xr, WqT, bq, SC_FOLD, Qb, nullptr, nullptr, 1024);

  k_cast_bf16<<<2048, 256, 0, stream>>>(xkv, Xr, B_ * TKV_ * DM_ / 4);
  k_gemm8<1, 256><<<dim3(8, 32), 512, 0, stream>>>(Xr, WkvT, bkv, 1.0f, Kb, Vb, nullptr, 1024);

  k_attn<<<dim3(8, B_ * H_), 256, 0, stream>>>(Qb, Kb, Vb, mask, cflag, Ob);

  k_gemm8<2, 128><<<dim3(8, 32), 512, 0, stream>>>(Ob, WoT, bo, 1.0f, nullptr, nullptr, out, 1024);
}

// Round 11
// 200.535 us; speedup vs baseline: 1.2390x; 1.0369x over previous
//
#include <hip/hip_runtime.h>
#include <hip/hip_bf16.h>

#define B_   4
#define TQ_  2048
#define TKV_ 2048
#define DM_  1024
#define H_   16
#define DH_  64

// 1/sqrt(DK) * log2(e), folded into Wq/bq so attention exp2 needs no scaling
#define SC_FOLD 0.18033688011112042f

using f32x4  = __attribute__((ext_vector_type(4))) float;
using f32x16 = __attribute__((ext_vector_type(16))) float;
using s16x8  = __attribute__((ext_vector_type(8))) short;

static __device__ __forceinline__ unsigned short f2bf(float f) {
  union { float f; unsigned int u; } v; v.f = f;
  unsigned int r = v.u + 0x7FFFu + ((v.u >> 16) & 1u);
  return (unsigned short)(r >> 16);
}
// packed f32 pair -> 2xbf16 (RNE) in one instruction
static __device__ __forceinline__ unsigned int pk2(float a, float b) {
  unsigned int r;
  asm("v_cvt_pk_bf16_f32 %0, %1, %2" : "=v"(r) : "v"(a), "v"(b));
  return r;
}
static __device__ __forceinline__ float max3f(float a, float b, float c) {
  float r;
  asm("v_max3_f32 %0, %1, %2, %3" : "=v"(r) : "v"(a), "v"(b), "v"(c));
  return r;
}

// async global->LDS, 16B per lane; LDS dest is wave-uniform base + lane*16
#define GL16(g, l)                                                          \
  __builtin_amdgcn_global_load_lds(                                         \
      (const __attribute__((address_space(1))) unsigned int*)(g),           \
      (__attribute__((address_space(3))) unsigned int*)(l), 16, 0, 0)

// ---------------- transpose + cast + scale: W[K][N] f32 -> WT[N][K] bf16 ----------------
__global__ __launch_bounds__(256) void k_transpose_cast(
    const float* __restrict__ W, unsigned short* __restrict__ WT, int K, int N,
    float scale) {
  __shared__ float t[64][65];
  int n0 = blockIdx.x * 64, k0 = blockIdx.y * 64;
  int tx = threadIdx.x & 63, ty = threadIdx.x >> 6;
#pragma unroll
  for (int i = 0; i < 64; i += 4)
    t[ty + i][tx] = W[(size_t)(k0 + ty + i) * N + n0 + tx];
  __syncthreads();
#pragma unroll
  for (int i = 0; i < 64; i += 4)
    WT[(size_t)(n0 + ty + i) * K + k0 + tx] = f2bf(t[tx][ty + i] * scale);
}

// ---------------- elementwise cast f32 -> bf16 ----------------
__global__ __launch_bounds__(256) void k_cast_bf16(
    const float* __restrict__ in, unsigned short* __restrict__ out, int n4) {
  for (int i = blockIdx.x * 256 + threadIdx.x; i < n4; i += gridDim.x * 256) {
    f32x4 v = *(const f32x4*)(in + (size_t)i * 4);
    unsigned long long u = (unsigned long long)pk2(v[0], v[1]) |
                           ((unsigned long long)pk2(v[2], v[3]) << 32);
    *(unsigned long long*)(out + (size_t)i * 4) = u;
  }
}

// ---------------- GEMM, 8-phase 256-row tile (T1+T2+T3+T4+T5) — unchanged R9 ----------------
template <int MODE, int BN>
__global__ __launch_bounds__(512, 2) void k_gemm8(
    const unsigned short* __restrict__ A, const unsigned short* __restrict__ BT,
    const float* __restrict__ bias, float bscale, unsigned short* __restrict__ out_a,
    unsigned short* __restrict__ out_b, float* __restrict__ out_f, int Kd) {
  constexpr int NI = BN / 64;
  constexpr int NH = NI / 2;
  __shared__ __align__(16) unsigned short As[2 * 256 * 64];
  __shared__ __align__(16) unsigned short Bs[2 * BN * 64];
  const int tid = threadIdx.x, lane = tid & 63, w = tid >> 6;
  const int wm = w >> 2, wn = w & 3;

  int nwg = gridDim.x * gridDim.y;
  int bid = blockIdx.y * gridDim.x + blockIdx.x;
  int cpx = nwg >> 3;
  int sw = (bid & 7) * cpx + (bid >> 3);
  int bx = sw % gridDim.x, by = sw / gridDim.x;
  int m0 = by * 256, n0 = bx * BN;

  const int strow = tid >> 3;
  const int sx = ((tid & 7) << 4) ^ ((strow & 7) << 4);
  const char* gA = (const char*)(A + (size_t)(m0 + strow) * Kd) + sx;
  const char* gB = (const char*)(BT + (size_t)(n0 + strow) * Kd) + sx;
  char* lA = (char*)As;
  char* lB = (char*)Bs;

#define ST_A(bf, c, k0) \
  GL16(gA + ((size_t)(c) * 64 * Kd + (size_t)(k0)) * 2, lA + (bf) * 32768 + (c) * 8192 + tid * 16)
#define ST_B(bf, c, k0) \
  GL16(gB + ((size_t)(c) * 64 * Kd + (size_t)(k0)) * 2, lB + (bf) * (BN * 128) + (c) * 8192 + tid * 16)

  f32x4 acc[8][NI];
#pragma unroll
  for (int i = 0; i < 8; ++i)
#pragma unroll
    for (int j = 0; j < NI; ++j) acc[i][j] = (f32x4){0.f, 0.f, 0.f, 0.f};

  s16x8 afr[4][2], bfr[NI][2];
  const int arow = wm * 128 + (lane & 15);
  const int brow = wn * (NI * 16) + (lane & 15);
  const int fcol = (lane >> 4) * 16;

#define RD_A(bf, r) (*(const s16x8*)(lA + (bf) * 32768 + (r) * 128 + ((fcol + _kk * 64) ^ (((r) & 7) << 4))))
#define RD_B(bf, r) (*(const s16x8*)(lB + (bf) * (BN * 128) + (r) * 128 + ((fcol + _kk * 64) ^ (((r) & 7) << 4))))

  const int nT = Kd >> 6;

  ST_B(0, 0, 0); ST_B(0, 1, 0);
  if (BN == 256) { ST_B(0, 2, 0); ST_B(0, 3, 0); }
  ST_A(0, 0, 0); ST_A(0, 2, 0);
  ST_A(0, 1, 0); ST_A(0, 3, 0);
  asm volatile("s_waitcnt vmcnt(2)" ::: "memory");
  __builtin_amdgcn_s_barrier();

#pragma unroll 1
  for (int t = 0; t < nT; ++t) {
    const int cur = t & 1, nxt = cur ^ 1;
    const int k1 = (t + 1) << 6;
    const bool st = (t + 1 < nT);

#pragma unroll
    for (int mi = 0; mi < 4; ++mi)
#pragma unroll
      for (int _kk = 0; _kk < 2; ++_kk) afr[mi][_kk] = RD_A(cur, arow + mi * 16);
#pragma unroll
    for (int ni = 0; ni < NH; ++ni)
#pragma unroll
      for (int _kk = 0; _kk < 2; ++_kk) bfr[ni][_kk] = RD_B(cur, brow + ni * 16);
    if (st) { ST_B(nxt, 0, k1); ST_B(nxt, 1, k1); }
    __builtin_amdgcn_s_barrier();
    __builtin_amdgcn_s_setprio(1);
#pragma unroll
    for (int mi = 0; mi < 4; ++mi)
#pragma unroll
      for (int ni = 0; ni < NH; ++ni)
#pragma unroll
        for (int kk = 0; kk < 2; ++kk)
          acc[mi][ni] = __builtin_amdgcn_mfma_f32_16x16x32_bf16(afr[mi][kk], bfr[ni][kk], acc[mi][ni], 0, 0, 0);
    __builtin_amdgcn_s_setprio(0);
    __builtin_amdgcn_s_barrier();

#pragma unroll
    for (int ni = NH; ni < NI; ++ni)
#pragma unroll
      for (int _kk = 0; _kk < 2; ++_kk) bfr[ni][_kk] = RD_B(cur, brow + ni * 16);
    if (st) {
      if (BN == 256) { ST_B(nxt, 2, k1); ST_B(nxt, 3, k1); }
      else           { ST_A(nxt, 0, k1); ST_A(nxt, 2, k1); }
    }
    if (st) asm volatile("s_waitcnt vmcnt(4)" ::: "memory");
    else    asm volatile("s_waitcnt vmcnt(0)" ::: "memory");
    __builtin_amdgcn_s_barrier();
    __builtin_amdgcn_s_setprio(1);
#pragma unroll
    for (int mi = 0; mi < 4; ++mi)
#pragma unroll
      for (int ni = NH; ni < NI; ++ni)
#pragma unroll
        for (int kk = 0; kk < 2; ++kk)
          acc[mi][ni] = __builtin_amdgcn_mfma_f32_16x16x32_bf16(afr[mi][kk], bfr[ni][kk], acc[mi][ni], 0, 0, 0);
    __builtin_amdgcn_s_setprio(0);
    __builtin_amdgcn_s_barrier();

#pragma unroll
    for (int mi = 0; mi < 4; ++mi)
#pragma unroll
      for (int _kk = 0; _kk < 2; ++_kk) afr[mi][_kk] = RD_A(cur, arow + (mi + 4) * 16);
    if (st) {
      if (BN == 256) { ST_A(nxt, 0, k1); ST_A(nxt, 2, k1); }
      else           { ST_A(nxt, 1, k1); ST_A(nxt, 3, k1); }
    }
    __builtin_amdgcn_s_barrier();
    __builtin_amdgcn_s_setprio(1);
#pragma unroll
    for (int mi = 0; mi < 4; ++mi)
#pragma unroll
      for (int ni = 0; ni < NH; ++ni)
#pragma unroll
        for (int kk = 0; kk < 2; ++kk)
          acc[mi + 4][ni] = __builtin_amdgcn_mfma_f32_16x16x32_bf16(afr[mi][kk], bfr[ni][kk], acc[mi + 4][ni], 0, 0, 0);
    __builtin_amdgcn_s_setprio(0);
    __builtin_amdgcn_s_barrier();

    if (st && BN == 256) { ST_A(nxt, 1, k1); ST_A(nxt, 3, k1); }
    asm volatile("s_waitcnt vmcnt(2)" ::: "memory");
    __builtin_amdgcn_s_barrier();
    __builtin_amdgcn_s_setprio(1);
#pragma unroll
    for (int mi = 0; mi < 4; ++mi)
#pragma unroll
      for (int ni = NH; ni < NI; ++ni)
#pragma unroll
        for (int kk = 0; kk < 2; ++kk)
          acc[mi + 4][ni] = __builtin_amdgcn_mfma_f32_16x16x32_bf16(afr[mi][kk], bfr[ni][kk], acc[mi + 4][ni], 0, 0, 0);
    __builtin_amdgcn_s_setprio(0);
    __builtin_amdgcn_s_barrier();
  }

#pragma unroll
  for (int mi = 0; mi < 8; ++mi) {
#pragma unroll
    for (int ni = 0; ni < NI; ++ni) {
      int col = n0 + wn * (NI * 16) + ni * 16 + (lane & 15);
      int rbase = m0 + wm * 128 + mi * 16 + (lane >> 4) * 4;
      float bv = bias[col] * bscale;
      if (MODE == 1 && col >= H_ * DH_) {
        int c2 = col - H_ * DH_;
        int h = c2 >> 6, d = c2 & 63;
        int b = rbase >> 11, tt = rbase & 2047;
        union { unsigned short h4[4]; unsigned long long u; } p;
#pragma unroll
        for (int r = 0; r < 4; ++r) p.h4[r] = f2bf(acc[mi][ni][r] + bv);
        *(unsigned long long*)(out_b + ((((size_t)b * H_ + h) * DH_ + d) * TKV_ + tt)) = p.u;
      } else {
#pragma unroll
        for (int r = 0; r < 4; ++r) {
          float v = acc[mi][ni][r] + bv;
          int m = rbase + r;
          if (MODE == 0) {
            int b = m >> 11, tt = m & 2047;
            int h = col >> 6, d = col & 63;
            out_a[(((size_t)b * H_ + h) * TQ_ + tt) * DH_ + d] = f2bf(v);
          } else if (MODE == 1) {
            int b = m >> 11, tt = m & 2047;
            int h = col >> 6, d = col & 63;
            out_a[(((size_t)b * H_ + h) * TKV_ + tt) * DH_ + d] = f2bf(v);
          } else {
            out_f[(size_t)m * DM_ + col] = v;
          }
        }
      }
    }
  }
#undef ST_A
#undef ST_B
#undef RD_A
#undef RD_B
}

// ---------------- flash attention: KVBLK=128, sub-tile causal gating ----------------
// grid (8, 64) x 256 threads = 4 waves x 32 q-rows; paired q-tiles (bx, 15-bx).
// Per 128-kv tile: reg-stage next tile before compute (T14), ds_write after the
// read-done barrier; 2 barriers per 128 kv (was per 64). Wave-uniform nact gates
// QK/softmax/PV at 32-kv sub-tile granularity (cuts diagonal waste).
__global__ __launch_bounds__(256, 2) void k_attn(
    const unsigned short* __restrict__ Qb, const unsigned short* __restrict__ Kb,
    const unsigned short* __restrict__ Vtb, const unsigned char* __restrict__ mask,
    const int* __restrict__ cflag, unsigned short* __restrict__ Ob) {
  __shared__ __align__(16) unsigned short Kt[128 * 64];  // [kv=128][d=64], XOR-swizzled
  __shared__ __align__(16) unsigned short Vt[64 * 128];  // [d=64][kv=128], XOR-swizzled
  __shared__ float bias_lds[128];
  __shared__ float red[4][32];
  __shared__ int s_any;

  // XCD head-locality swizzle: 8 q-blocks of a head on one XCD
  int bid = blockIdx.y * gridDim.x + blockIdx.x;
  int r8 = bid & 7, q8 = bid >> 3;
  int bh = r8 * 8 + (q8 >> 3);
  int bx = q8 & 7;

  int b = bh >> 4, h = bh & 15;
  int tid = threadIdx.x, lane = tid & 63, w = tid >> 6;
  int hi = lane >> 5, l31 = lane & 31, l7 = lane & 7;
  const unsigned short* Qp = Qb + (size_t)bh * TQ_ * DH_;
  const char* Kp = (const char*)(Kb + (size_t)bh * TKV_ * DH_);
  const char* Vp = (const char*)(Vtb + (size_t)bh * DH_ * TKV_);
  const unsigned char* mp = mask + (size_t)b * TKV_;
  int causal = cflag[0];
  char* kbase = (char*)Kt;
  char* vbase = (char*)Vt;

  // staging: K 128x128B rows (4x16B/thread), V 64x256B rows (4x16B/thread)
  int st_r4 = tid >> 2;            // 0..63
  int st_c4 = (tid & 3) * 16;      // 0,16,32,48
  s16x8 pKr[4], pVr[4];

#define LOAD_KV(kv0)                                                          \
  {                                                                           \
    _Pragma("unroll")                                                         \
    for (int p = 0; p < 4; ++p) {                                             \
      int krow = (p >> 1) * 64 + st_r4;                                       \
      int kx = st_c4 + (p & 1) * 64;                                          \
      pKr[p] = *(const s16x8*)(Kp + ((size_t)((kv0) + krow) * 128 + kx));     \
      int vx = st_c4 + p * 64;                                                \
      pVr[p] = *(const s16x8*)(Vp + (((size_t)st_r4 * TKV_ + (kv0)) * 2 + vx)); \
    }                                                                         \
  }
#define WRITE_KV()                                                            \
  {                                                                           \
    _Pragma("unroll")                                                         \
    for (int p = 0; p < 4; ++p) {                                             \
      int krow = (p >> 1) * 64 + st_r4;                                       \
      int kx = st_c4 + (p & 1) * 64;                                          \
      *(s16x8*)(kbase + krow * 128 + (kx ^ ((st_r4 & 7) << 4))) = pKr[p];     \
      int vx = st_c4 + p * 64;                                                \
      *(s16x8*)(vbase + st_r4 * 256 + (vx ^ ((st_r4 & 7) << 4))) = pVr[p];    \
    }                                                                         \
  }

  if (tid == 0) s_any = 0;
  __syncthreads();
  {
    int any = 0;
    for (int i = tid; i < TKV_; i += 256) any |= mp[i];
    if (any) s_any = 1;
  }
  __syncthreads();
  const int has_mask = s_any;

#pragma unroll 1
  for (int pass = 0; pass < 2; ++pass) {
    int qb = (pass ? (15 - bx) : bx) * 128;
    int qw = qb + w * 32;
    int qrow = qw + l31;

    s16x8 bQ[4];
#pragma unroll
    for (int kk = 0; kk < 4; ++kk)
      bQ[kk] = *(const s16x8*)(Qp + (size_t)qrow * DH_ + kk * 16 + hi * 8);

    f32x16 accO[2];
#pragma unroll
    for (int i = 0; i < 16; ++i) { accO[0][i] = 0.f; accO[1][i] = 0.f; }
    float m_run = -INFINITY, l_run = 0.f;

    int nT = (causal ? (qb + 128) : TKV_) >> 7;

    LOAD_KV(0);
    WRITE_KV();
    if (has_mask && tid < 128) bias_lds[tid] = mp[tid] ? -1e30f : 0.0f;
    __syncthreads();

#pragma unroll 1
    for (int it = 0; it < nT; ++it) {
      int kv0 = it << 7;
      if (it + 1 < nT) LOAD_KV(kv0 + 128);

      // wave-uniform active sub-tile count (32-kv granularity)
      int nact = 4;
      if (causal) {
        int rem = qw + 31 - kv0;
        nact = rem < 0 ? 0 : ((rem >> 5) + 1);
        if (nact > 4) nact = 4;
      }

      if (nact > 0) {
        f32x16 sT[4];
        __builtin_amdgcn_s_setprio(1);
#pragma unroll
        for (int s = 0; s < 4; ++s) {
          if (s < nact) {
#pragma unroll
            for (int i = 0; i < 16; ++i) sT[s][i] = 0.f;
#pragma unroll
            for (int kk = 0; kk < 4; ++kk) {
              s16x8 aK = *(const s16x8*)(kbase + (s * 32 + l31) * 128 +
                                         ((kk * 32 + hi * 16) ^ (l7 << 4)));
              sT[s] = __builtin_amdgcn_mfma_f32_32x32x16_bf16(aK, bQ[kk], sT[s], 0, 0, 0);
            }
          }
        }
        __builtin_amdgcn_s_setprio(0);

        // masks + row-max over active sub-tiles (4 parallel accumulators)
        float a0 = -INFINITY, a1 = -INFINITY, a2 = -INFINITY, a3 = -INFINITY;
#pragma unroll
        for (int s = 0; s < 4; ++s) {
          if (s < nact) {
            int diag_s = causal && (kv0 + s * 32 + 31 > qw);  // wave-uniform
            if (diag_s || has_mask) {
#pragma unroll
              for (int r = 0; r < 16; ++r) {
                int kvloc = s * 32 + (r & 3) + 8 * (r >> 2) + 4 * hi;
                float sv = sT[s][r];
                if (has_mask) sv += bias_lds[kvloc];
                if (diag_s && (kv0 + kvloc) > qrow) sv = -1e30f;
                sT[s][r] = sv;
              }
            }
#pragma unroll
            for (int r = 0; r < 16; r += 4) {
              a0 = fmaxf(a0, sT[s][r + 0]); a1 = fmaxf(a1, sT[s][r + 1]);
              a2 = fmaxf(a2, sT[s][r + 2]); a3 = fmaxf(a3, sT[s][r + 3]);
            }
          }
        }
        float mx = max3f(max3f(a0, a1, a2), a3, -3.0e30f);
        mx = fmaxf(mx, __shfl_xor(mx, 32));

        // T13 defer-rescale
        if (!__all(mx - m_run <= 8.0f)) {
          float mnew = fmaxf(m_run, mx);
          float sc_o = exp2f(m_run - mnew);
          m_run = mnew;
          l_run *= sc_o;
          red[w][l31] = sc_o;
#pragma unroll
          for (int r = 0; r < 16; ++r) {
            float f = red[w][(r & 3) + 8 * (r >> 2) + 4 * hi];
            accO[0][r] *= f;
            accO[1][r] *= f;
          }
        }

        // exp + 4-way parallel partial sums (active sub-tiles only)
        float s0acc = 0.f, s1acc = 0.f, s2acc = 0.f, s3acc = 0.f;
#pragma unroll
        for (int s = 0; s < 4; ++s) {
          if (s < nact) {
#pragma unroll
            for (int r = 0; r < 16; r += 4) {
              float p0 = exp2f(sT[s][r + 0] - m_run);
              float p1 = exp2f(sT[s][r + 1] - m_run);
              float p2 = exp2f(sT[s][r + 2] - m_run);
              float p3 = exp2f(sT[s][r + 3] - m_run);
              sT[s][r + 0] = p0; sT[s][r + 1] = p1;
              sT[s][r + 2] = p2; sT[s][r + 3] = p3;
              s0acc += p0; s1acc += p1; s2acc += p2; s3acc += p3;
            }
          }
        }
        float ls = (s0acc + s1acc) + (s2acc + s3acc);
        ls += __shfl_xor(ls, 32);
        l_run += ls;

        // P -> A-frag + PV, per 16-kv chunk c (skip inactive sub-tiles)
#pragma unroll
        for (int c = 0; c < 8; ++c) {
          if ((c >> 1) < nact) {
            int s = c >> 1, kk = c & 1;
            unsigned int x0 = pk2(sT[s][8 * kk + 0], sT[s][8 * kk + 1]);
            unsigned int y0 = pk2(sT[s][8 * kk + 2], sT[s][8 * kk + 3]);
            unsigned int x1 = pk2(sT[s][8 * kk + 4], sT[s][8 * kk + 5]);
            unsigned int y1 = pk2(sT[s][8 * kk + 6], sT[s][8 * kk + 7]);
            unsigned int sx0 = __shfl_xor(x0, 32), sy0 = __shfl_xor(y0, 32);
            unsigned int sx1 = __shfl_xor(x1, 32), sy1 = __shfl_xor(y1, 32);
            union { unsigned int u[4]; s16x8 v; } pf;
            pf.u[0] = hi ? sx1 : x0;
            pf.u[1] = hi ? sy1 : y0;
            pf.u[2] = hi ? x1 : sx0;
            pf.u[3] = hi ? y1 : sy0;
            __builtin_amdgcn_s_setprio(1);
#pragma unroll
            for (int dt = 0; dt < 2; ++dt) {
              s16x8 vf = *(const s16x8*)(vbase + (dt * 32 + l31) * 256 +
                                         ((c * 32 + hi * 16) ^ (l7 << 4)));
              accO[dt] = __builtin_amdgcn_mfma_f32_32x32x16_bf16(pf.v, vf, accO[dt], 0, 0, 0);
            }
            __builtin_amdgcn_s_setprio(0);
          }
        }
      }

      __syncthreads();  // everyone done reading tile it
      if (it + 1 < nT) {
        WRITE_KV();     // compiler waits vmcnt for pKr/pVr
        if (has_mask && tid < 128) bias_lds[tid] = mp[kv0 + 128 + tid] ? -1e30f : 0.0f;
      }
      __syncthreads();  // writes visible
    }

    // epilogue
    red[w][l31] = 1.0f / l_run;
#pragma unroll
    for (int r = 0; r < 16; ++r) {
      int R = (r & 3) + 8 * (r >> 2) + 4 * hi;
      float f = red[w][R];
      int qg = qw + R;
      size_t base = ((size_t)b * TQ_ + qg) * DM_ + h * DH_ + l31;
      Ob[base] = f2bf(accO[0][r] * f);
      Ob[base + 32] = f2bf(accO[1][r] * f);
    }
  }
#undef LOAD_KV
#undef WRITE_KV
}

extern "C" void kernel_launch(void* const* d_in, const int* in_sizes, int n_in,
                              void* d_out, int out_size, void* d_ws, size_t ws_size,
                              hipStream_t stream) {
  const float* xq  = (const float*)d_in[0];
  const float* xkv = (const float*)d_in[1];
  const unsigned char* mask = (const unsigned char*)d_in[2];
  const float* Wq  = (const float*)d_in[3];
  const float* bq  = (const float*)d_in[4];
  const float* Wkv = (const float*)d_in[5];
  const float* bkv = (const float*)d_in[6];
  const float* Wo  = (const float*)d_in[7];
  const float* bo  = (const float*)d_in[8];
  const int* cflag = (const int*)d_in[9];
  float* out = (float*)d_out;

  char* ws = (char*)d_ws;
  unsigned short* WqT  = (unsigned short*)(ws);                       // 2 MiB
  unsigned short* WkvT = (unsigned short*)(ws + ((size_t)2 << 20));   // 4 MiB
  unsigned short* WoT  = (unsigned short*)(ws + ((size_t)6 << 20));   // 2 MiB
  unsigned short* Qb   = (unsigned short*)(ws + ((size_t)8 << 20));   // [B,H,TQ,64]
  unsigned short* Kb   = (unsigned short*)(ws + ((size_t)24 << 20));  // [B,H,TKV,64]
  unsigned short* Vb   = (unsigned short*)(ws + ((size_t)40 << 20));  // [B,H,64,TKV]
  unsigned short* Xr   = (unsigned short*)(ws + ((size_t)56 << 20));  // Aq -> Akv -> Ob
  unsigned short* Ob   = Xr;

  k_transpose_cast<<<dim3(16, 16), 256, 0, stream>>>(Wq, WqT, 1024, 1024, SC_FOLD);
  k_transpose_cast<<<dim3(32, 16), 256, 0, stream>>>(Wkv, WkvT, 1024, 2048, 1.0f);
  k_transpose_cast<<<dim3(16, 16), 256, 0, stream>>>(Wo, WoT, 1024, 1024, 1.0f);

  k_cast_bf16<<<2048, 256, 0, stream>>>(xq, Xr, B_ * TQ_ * DM_ / 4);
  k_gemm8<0, 128><<<dim3(8, 32), 512, 0, stream>>>(Xr, WqT, bq, SC_FOLD, Qb, nullptr, nullptr, 1024);

  k_cast_bf16<<<2048, 256, 0, stream>>>(xkv, Xr, B_ * TKV_ * DM_ / 4);
  k_gemm8<1, 256><<<dim3(8, 32), 512, 0, stream>>>(Xr, WkvT, bkv, 1.0f, Kb, Vb, nullptr, 1024);

  k_attn<<<dim3(8, B_ * H_), 256, 0, stream>>>(Qb, Kb, Vb, mask, cflag, Ob);

  k_gemm8<2, 128><<<dim3(8, 32), 512, 0, stream>>>(Ob, WoT, bo, 1.0f, nullptr, nullptr, out, 1024);
}